// Round 1
// baseline (417.970 us; speedup 1.0000x reference)
//
#include <hip/hip_runtime.h>

#define N_NODES 50000
#define E_EDGES 800000
#define M_ROWS  12500
#define IN_DIM  256
#define HID     128
#define OUT_DIM 64
#define EPS     1e-5f
#define SLOPE   0.1f
#define NSB     25          // super-buckets of 4096 nodes over [0, 2N)
#define SB_CAP  (96 * 1024) // >> 64K avg +129 sigma; fixed inputs safe

typedef unsigned short u16;
typedef unsigned int u32;
typedef __attribute__((ext_vector_type(8))) short short8;
typedef __attribute__((ext_vector_type(4))) float f32x4;

__device__ __forceinline__ float leaky_f(float x) { return x >= 0.f ? x : SLOPE * x; }

__device__ __forceinline__ u16 f2bf(float f) {
  u32 x = __float_as_uint(f);
  return (u16)((x + 0x7fffu + ((x >> 16) & 1u)) >> 16);
}
__device__ __forceinline__ float bf2f(u16 u) { return __uint_as_float((u32)u << 16); }
__device__ __forceinline__ float bf2f_lo(u32 v) { return __uint_as_float(v << 16); }
__device__ __forceinline__ float bf2f_hi(u32 v) { return __uint_as_float(v & 0xffff0000u); }

struct GArgs {
  const void* A1[2];
  const void* A2[2];
  const u16* Bt[2];
  const float* bias[2];
  u16* Cb[2];
  float* bnsum[2];
  float* bnss[2];
  const int* seg[2];
  const int* cnt[2];
  float* y[2];
};

struct EdgeArgs {
  const int* src[2];
  const int* dst[2];
  const int* seg[2];
};

struct CvtArgs {
  const float* W[12];
  u16* Bt;
};

// ---------------------------------------------------------------------------
// Barrier-free streaming MFMA GEMM.
// Each wave owns a 32-row x BN strip: A fragments load global->VGPR directly
// (16B/lane, 64B/row chunks), B fragments load directly from L2-resident Bt.
// KTOT is a template constant -> full K unroll, zero __syncthreads in the
// compute path, deep outstanding-load pipeline (this GEMM is HBM-stream-bound:
// K=256 only; the old 2-barrier-per-K-step LDS loop was latency-bound at 13%
// of HBM peak).
// MODE 0 ENCODE: A1 = f32; C = bf16 leaky; BN col stats via LDS block-reduce.
// MODE 1 LAYER : A1,A2 = bf16 (K split 128+128); C = bf16 leaky (in-place safe:
//                blocks only write rows they own; tail clamp targets stay
//                wave-local or feed never-stored acc rows).
// MODE 2 POOL  : A1 = bf16; no act; atomicAdd (v*w) into y[seg[row]][col].
// ---------------------------------------------------------------------------
template <int BN, int MODE, int KTOT>
__global__ __launch_bounds__(256) void gemm_stream(GArgs ga, int nrows) {
  constexpr int NI = BN / 16;
  constexpr int KT = KTOT / 32;
  __shared__ float redS[(MODE == 0) ? 128 : 1];
  __shared__ float redQ[(MODE == 0) ? 128 : 1];

  const int pb = blockIdx.y;
  const int t = threadIdx.x;
  const int w = t >> 6, lane = t & 63;
  const int laneM = lane & 15, kg = lane >> 4;
  const int r0 = blockIdx.x * 128 + w * 32;

  if constexpr (MODE == 0) {
    if (t < 128) { redS[t] = 0.f; redQ[t] = 0.f; }
    __syncthreads();
  }

  const u16* Bt = ga.Bt[pb];
  const float* bias = ga.bias[pb];

  // per-lane A row indices for the two 16-row sub-tiles (clamped for tail)
  int ra0 = r0 + laneM;
  int ra1 = r0 + 16 + laneM;
  if (ra0 >= nrows) ra0 = nrows - 1;
  if (ra1 >= nrows) ra1 = nrows - 1;

  // B fragment base pointers (col = ni*16 + laneM, k-offset kg*8)
  const u16* bbase[NI];
#pragma unroll
  for (int ni = 0; ni < NI; ni++)
    bbase[ni] = Bt + (size_t)(ni * 16 + laneM) * KTOT + kg * 8;

  // A fragment base pointers
  const float* af32[2];
  const u16* ab1[2];
  const u16* ab2[2];
  if constexpr (MODE == 0) {
    const float* A = (const float*)ga.A1[pb];
    af32[0] = A + (size_t)ra0 * KTOT + kg * 8;
    af32[1] = A + (size_t)ra1 * KTOT + kg * 8;
  } else {
    const u16* A1 = (const u16*)ga.A1[pb];
    ab1[0] = A1 + (size_t)ra0 * HID + kg * 8;
    ab1[1] = A1 + (size_t)ra1 * HID + kg * 8;
    if constexpr (MODE == 1) {
      const u16* A2 = (const u16*)ga.A2[pb];
      ab2[0] = A2 + (size_t)ra0 * HID + kg * 8;
      ab2[1] = A2 + (size_t)ra1 * HID + kg * 8;
    }
  }

  f32x4 acc[2][NI];
#pragma unroll
  for (int mi = 0; mi < 2; mi++)
#pragma unroll
    for (int ni = 0; ni < NI; ni++) acc[mi][ni] = (f32x4){0.f, 0.f, 0.f, 0.f};

#pragma unroll
  for (int kt = 0; kt < KT; kt++) {
    const int k0 = kt * 32;
    short8 af[2];
#pragma unroll
    for (int mi = 0; mi < 2; mi++) {
      if constexpr (MODE == 0) {
        const float4* p = (const float4*)(af32[mi] + k0);
        float4 v0 = p[0], v1 = p[1];
        short8 s;
        s[0] = (short)f2bf(v0.x); s[1] = (short)f2bf(v0.y);
        s[2] = (short)f2bf(v0.z); s[3] = (short)f2bf(v0.w);
        s[4] = (short)f2bf(v1.x); s[5] = (short)f2bf(v1.y);
        s[6] = (short)f2bf(v1.z); s[7] = (short)f2bf(v1.w);
        af[mi] = s;
      } else if constexpr (MODE == 1) {
        const u16* p = (k0 < 128) ? (ab1[mi] + k0) : (ab2[mi] + (k0 - 128));
        af[mi] = *(const short8*)p;
      } else {
        af[mi] = *(const short8*)(ab1[mi] + k0);
      }
    }
    short8 bfv[NI];
#pragma unroll
    for (int ni = 0; ni < NI; ni++)
      bfv[ni] = *(const short8*)(bbase[ni] + k0);
#pragma unroll
    for (int mi = 0; mi < 2; mi++)
#pragma unroll
      for (int ni = 0; ni < NI; ni++)
        acc[mi][ni] = __builtin_amdgcn_mfma_f32_16x16x32_bf16(
            af[mi], bfv[ni], acc[mi][ni], 0, 0, 0);
  }

  // ---- epilogue ----
  float bcol[NI];
#pragma unroll
  for (int ni = 0; ni < NI; ni++) bcol[ni] = bias[ni * 16 + laneM];

  float ssum[NI], ssq[NI];
#pragma unroll
  for (int ni = 0; ni < NI; ni++) { ssum[ni] = 0.f; ssq[ni] = 0.f; }

#pragma unroll
  for (int mi = 0; mi < 2; mi++) {
#pragma unroll
    for (int r = 0; r < 4; r++) {
      int gr = r0 + mi * 16 + kg * 4 + r;
      if (gr >= nrows) continue;
      float pw = 0.f;
      int sI = 0;
      if constexpr (MODE == 2) {
        sI = ga.seg[pb][gr];
        int cv = ga.cnt[pb][sI];
        pw = 1.f / (float)(cv > 1 ? cv : 1);
      }
#pragma unroll
      for (int ni = 0; ni < NI; ni++) {
        int col = ni * 16 + laneM;
        float v = acc[mi][ni][r] + bcol[ni];
        if constexpr (MODE == 0) {
          v = leaky_f(v);
          ga.Cb[pb][(size_t)gr * BN + col] = f2bf(v);
          ssum[ni] += v;
          ssq[ni] += v * v;
        } else if constexpr (MODE == 1) {
          v = leaky_f(v);
          ga.Cb[pb][(size_t)gr * BN + col] = f2bf(v);
        } else {
          atomicAdd(&ga.y[pb][(size_t)sI * OUT_DIM + col], v * pw);
        }
      }
    }
  }

  if constexpr (MODE == 0) {
#pragma unroll
    for (int ni = 0; ni < NI; ni++) {
      float a = ssum[ni], b = ssq[ni];
      a += __shfl_xor(a, 16); a += __shfl_xor(a, 32);
      b += __shfl_xor(b, 16); b += __shfl_xor(b, 32);
      if (kg == 0) {
        atomicAdd(&redS[ni * 16 + laneM], a);
        atomicAdd(&redQ[ni * 16 + laneM], b);
      }
    }
    __syncthreads();
    if (t < 128) {
      atomicAdd(&ga.bnsum[pb][t], redS[t]);
      atomicAdd(&ga.bnss[pb][t], redQ[t]);
    }
  }
}

// Weights -> bf16 transposed Bt[n][k]; SKIPS Bt0 (folded later with BN affine).
__global__ __launch_bounds__(256) void cvt_weightsA(CvtArgs a) {
  int i = blockIdx.x * 256 + threadIdx.x;
  if (i >= 2 * 106496) return;
  int p = i >= 106496;
  int j = i - p * 106496;
  const float* const* W = a.W + p * 6;
  u16* out = a.Bt + (size_t)p * 106496;
  if (j < 32768) {
    int n = j >> 8, k = j & 255;
    out[j] = f2bf(W[0][k * 128 + n]);
  } else if (j < 65536) {
    return;
  } else if (j < 98304) {
    int q = j - 65536, n = q >> 8, k = q & 255;
    out[j] = f2bf(k < 128 ? W[3][k * 128 + n] : W[4][(k - 128) * 128 + n]);
  } else {
    int q = j - 98304, n = q >> 7, k = q & 127;
    out[j] = f2bf(W[5][k * 64 + n]);
  }
}

// abc layout: a[256] | c[256] | nc[256] | bias0p[256]
__global__ void bn_final(const float* __restrict__ bnstat,
                         const float* __restrict__ g0, const float* __restrict__ b0,
                         const float* __restrict__ g1, const float* __restrict__ b1,
                         float* __restrict__ abc) {
  int t = threadIdx.x;  // 256
  int p = t >> 7, cix = t & 127;
  const float* bs = bnstat + p * 256;
  float mu = bs[cix] * (1.f / N_NODES);
  float var = bs[128 + cix] * (1.f / N_NODES) - mu * mu;
  float rs = rsqrtf(var + EPS);
  const float* g = p ? g1 : g0;
  const float* b = p ? b1 : b0;
  float av = g[cix] * rs;
  float cv = b[cix] - mu * av;
  abc[t] = av;
  abc[256 + t] = cv;
  abc[512 + t] = (av != 0.f) ? (-cv / av) : 0.f;
}

// Fold BN affine into layer-0 weights.
__global__ __launch_bounds__(256) void cvt_fold(
    const float* __restrict__ Wl0_0, const float* __restrict__ Wr0_0,
    const float* __restrict__ Wl0_1, const float* __restrict__ Wr0_1,
    const float* __restrict__ b0_0, const float* __restrict__ b0_1,
    float* __restrict__ abc, u16* __restrict__ BtAll) {
  int i = blockIdx.x * 256 + threadIdx.x;
  if (i < 65536) {
    int p = i >> 15, q = i & 32767;
    int n = q >> 8, k = q & 255;
    const float* Wl = p ? Wl0_1 : Wl0_0;
    const float* Wr = p ? Wr0_1 : Wr0_0;
    float wv = (k < 128) ? Wl[k * 128 + n] : Wr[(k - 128) * 128 + n];
    float av = abc[p * 128 + (k & 127)];
    BtAll[(size_t)p * 106496 + 32768 + q] = f2bf(wv * av);
  } else if (i < 65536 + 256) {
    int j = i - 65536;
    int p = j >> 7, n = j & 127;
    const float* Wl = p ? Wl0_1 : Wl0_0;
    const float* Wr = p ? Wr0_1 : Wr0_0;
    const float* c = abc + 256 + p * 128;
    float s = (p ? b0_1 : b0_0)[n];
    for (int k = 0; k < 128; k++) s += c[k] * (Wl[k * 128 + n] + Wr[k * 128 + n]);
    abc[768 + j] = s;
  }
}

// pooling counts
__global__ void cnt_count(EdgeArgs ea, int* __restrict__ cnt) {
  int i = blockIdx.x * blockDim.x + threadIdx.x;
  if (i < 2 * N_NODES) {
    int p = i >= N_NODES;
    int k = i - p * N_NODES;
    atomicAdd(&cnt[p * M_ROWS + ea.seg[p][k]], 1);
  }
}

// --------- Phase A: partition edges into NSB super-buckets ------------------
// packed: dst_local(12b) << 17 | src(17b). Tile = 2048 edges, block-local
// counting sort, contiguous chunk copy-out (full-line single-CU writes).
__global__ __launch_bounds__(256) void part_edges(EdgeArgs ea, u32* __restrict__ sbuf,
                                                  int* __restrict__ gcursor) {
  __shared__ u32 lpack[2048];
  __shared__ int hist[NSB], base[NSB], gbase[NSB], lofs[NSB];
  int t = threadIdx.x;
  int e0 = blockIdx.x * 2048;
  if (t < NSB) hist[t] = 0;
  __syncthreads();
  u32 myp[8];
  int myb[8];
#pragma unroll
  for (int q = 0; q < 8; q++) {
    int i = e0 + q * 256 + t;
    int b = -1;
    u32 pk = 0;
    if (i < 2 * E_EDGES) {
      int p = i >= E_EDGES;
      int j = i - p * E_EDGES;
      int d = p * N_NODES + ea.dst[p][j];
      int s = ea.src[p][j];
      b = d >> 12;
      pk = ((u32)(d & 4095) << 17) | (u32)s;
      atomicAdd(&hist[b], 1);
    }
    myb[q] = b;
    myp[q] = pk;
  }
  __syncthreads();
  if (t == 0) {
    int acc = 0;
    for (int b = 0; b < NSB; b++) { base[b] = acc; acc += hist[b]; }
  }
  __syncthreads();
  if (t < NSB) {
    lofs[t] = 0;
    gbase[t] = atomicAdd(&gcursor[t], hist[t]);
  }
  __syncthreads();
#pragma unroll
  for (int q = 0; q < 8; q++) {
    if (myb[q] >= 0) {
      int pos = atomicAdd(&lofs[myb[q]], 1);
      lpack[base[myb[q]] + pos] = myp[q];
    }
  }
  __syncthreads();
  for (int b = 0; b < NSB; b++) {
    int n = hist[b], lb = base[b], gb = gbase[b];
    for (int k = t; k < n; k += 256)
      sbuf[(size_t)b * SB_CAP + gb + k] = lpack[lb + k];
  }
}

// --------- Phase B: per-super-bucket CSR build (one block per bucket) -------
__global__ __launch_bounds__(1024) void build_csr(
    const u32* __restrict__ sbuf, const int* __restrict__ gtot,
    int* __restrict__ offs, float* __restrict__ dinv, u16* __restrict__ colu) {
  __shared__ int ldeg[4096];
  __shared__ int lcur[4096];
  __shared__ int wsum[16];
  __shared__ int sb_tot[NSB];
  int b = blockIdx.x, t = threadIdx.x;
  if (t < NSB) sb_tot[t] = gtot[t];
  for (int k = t; k < 4096; k += 1024) ldeg[k] = 0;
  __syncthreads();
  int edge_base = 0;
  for (int i = 0; i < b; i++) edge_base += sb_tot[i];
  int cnt = sb_tot[b];
  int node0 = b << 12;
  int nend = 2 * N_NODES - node0;
  if (nend > 4096) nend = 4096;
  const u32* me = sbuf + (size_t)b * SB_CAP;
  for (int k = t; k < cnt; k += 1024) atomicAdd(&ldeg[me[k] >> 17], 1);
  __syncthreads();
  // block scan over 4096 (each thread: 4 consecutive)
  int d0 = ldeg[4 * t], d1 = ldeg[4 * t + 1], d2 = ldeg[4 * t + 2], d3 = ldeg[4 * t + 3];
  int ts = d0 + d1 + d2 + d3;
  int lane = t & 63, wid = t >> 6;
  int incl = ts;
#pragma unroll
  for (int off = 1; off < 64; off <<= 1) {
    int u = __shfl_up(incl, off, 64);
    if (lane >= off) incl += u;
  }
  if (lane == 63) wsum[wid] = incl;
  __syncthreads();
  if (t < 64) {
    int v = (t < 16) ? wsum[t] : 0;
    int iv = v;
#pragma unroll
    for (int off = 1; off < 16; off <<= 1) {
      int u = __shfl_up(iv, off, 64);
      if (t >= off) iv += u;
    }
    if (t < 16) wsum[t] = iv - v;
  }
  __syncthreads();
  int ex = wsum[wid] + incl - ts;
  int e1 = ex + d0, e2 = e1 + d1, e3 = e2 + d2;
  int n0 = node0 + 4 * t;
  int lexp[4] = {ex, e1, e2, e3};
  int ldg[4] = {d0, d1, d2, d3};
#pragma unroll
  for (int k = 0; k < 4; k++) {
    if (4 * t + k < nend) {
      offs[n0 + k] = edge_base + lexp[k];
      dinv[n0 + k] = ldg[k] > 0 ? 1.f / (float)ldg[k] : -1.f;
    }
    lcur[4 * t + k] = lexp[k];
  }
  __syncthreads();
  for (int k = t; k < cnt; k += 1024) {
    u32 v = me[k];
    int pos = atomicAdd(&lcur[v >> 17], 1);
    colu[edge_base + pos] = (u16)(v & 0x1FFFFu);
  }
  if (b == 0 && t == 0) offs[2 * N_NODES] = 2 * E_EDGES;
}

// --------- mean-aggregate: 1 wave/node, lanes split into 2 edge-halves ------
// lane<32: edge j, lane>=32: edge j+1; each lane loads 8B (4 bf16 cols).
// dinv<0 marks deg==0 -> nc[panel][col] (BN-fold patch or zeros).
__global__ __launch_bounds__(256) void aggregate_bf16(
    const u16* __restrict__ h, const u16* __restrict__ colu,
    const int* __restrict__ offs, const float* __restrict__ dinv,
    const float* __restrict__ nc, u16* __restrict__ agg) {
  int gw = (blockIdx.x * 256 + threadIdx.x) >> 6;
  int lane = threadIdx.x & 63;
  if (gw >= 2 * N_NODES) return;
  int panel = gw >= N_NODES;
  const uint2* hp = (const uint2*)(h + (size_t)panel * N_NODES * 128);
  int half = lane >> 5, li = lane & 31;
  int s = offs[gw], e = offs[gw + 1];
  float a0 = 0.f, a1 = 0.f, a2 = 0.f, a3 = 0.f;
  int j = s;
  for (; j + 8 <= e; j += 8) {
    int c0 = colu[j + half], c1 = colu[j + 2 + half];
    int c2 = colu[j + 4 + half], c3 = colu[j + 6 + half];
    uint2 v0 = hp[(size_t)c0 * 32 + li];
    uint2 v1 = hp[(size_t)c1 * 32 + li];
    uint2 v2 = hp[(size_t)c2 * 32 + li];
    uint2 v3 = hp[(size_t)c3 * 32 + li];
    a0 += (bf2f_lo(v0.x) + bf2f_lo(v1.x)) + (bf2f_lo(v2.x) + bf2f_lo(v3.x));
    a1 += (bf2f_hi(v0.x) + bf2f_hi(v1.x)) + (bf2f_hi(v2.x) + bf2f_hi(v3.x));
    a2 += (bf2f_lo(v0.y) + bf2f_lo(v1.y)) + (bf2f_lo(v2.y) + bf2f_lo(v3.y));
    a3 += (bf2f_hi(v0.y) + bf2f_hi(v1.y)) + (bf2f_hi(v2.y) + bf2f_hi(v3.y));
  }
  for (; j + 2 <= e; j += 2) {
    int c = colu[j + half];
    uint2 v = hp[(size_t)c * 32 + li];
    a0 += bf2f_lo(v.x);
    a1 += bf2f_hi(v.x);
    a2 += bf2f_lo(v.y);
    a3 += bf2f_hi(v.y);
  }
  if (j < e) {
    int c = colu[j];
    uint2 v = hp[(size_t)c * 32 + li];
    if (half == 0) {
      a0 += bf2f_lo(v.x);
      a1 += bf2f_hi(v.x);
      a2 += bf2f_lo(v.y);
      a3 += bf2f_hi(v.y);
    }
  }
  a0 += __shfl_xor(a0, 32);
  a1 += __shfl_xor(a1, 32);
  a2 += __shfl_xor(a2, 32);
  a3 += __shfl_xor(a3, 32);
  if (half == 0) {
    float di = dinv[gw];
    float o0, o1, o2, o3;
    if (di < 0.f) {
      const float* np = nc + panel * 128 + li * 4;
      o0 = np[0]; o1 = np[1]; o2 = np[2]; o3 = np[3];
    } else {
      o0 = a0 * di; o1 = a1 * di; o2 = a2 * di; o3 = a3 * di;
    }
    uint2 o;
    o.x = ((u32)f2bf(o1) << 16) | (u32)f2bf(o0);
    o.y = ((u32)f2bf(o3) << 16) | (u32)f2bf(o2);
    ((uint2*)agg)[(size_t)gw * 32 + li] = o;
  }
}

__global__ __launch_bounds__(256) void mse_kernel(const float* __restrict__ yb,
                                                  const float* __restrict__ x0,
                                                  const float* __restrict__ x1,
                                                  float* __restrict__ acc) {
  __shared__ float ls[256];
  int pb = blockIdx.y;
  const float* y = yb + (size_t)pb * M_ROWS * OUT_DIM;
  const float* x = pb ? x1 : x0;
  float s = 0.f;
  for (int i = blockIdx.x * 256 + threadIdx.x; i < M_ROWS * OUT_DIM; i += gridDim.x * 256) {
    float d = y[i] - x[i];
    s += d * d;
  }
  ls[threadIdx.x] = s;
  __syncthreads();
  for (int o = 128; o > 0; o >>= 1) {
    if (threadIdx.x < o) ls[threadIdx.x] += ls[threadIdx.x + o];
    __syncthreads();
  }
  if (threadIdx.x == 0) atomicAdd(&acc[pb], ls[0]);
}

__global__ void finalize(const float* __restrict__ acc, float* __restrict__ out) {
  int t = threadIdx.x;
  if (t < 2) out[t] = acc[t] * (1.f / (float)(M_ROWS * OUT_DIM));
}

// ---------------------------------------------------------------------------
extern "C" void kernel_launch(void* const* d_in, const int* in_sizes, int n_in,
                              void* d_out, int out_size, void* d_ws, size_t ws_size,
                              hipStream_t stream) {
  (void)in_sizes; (void)n_in; (void)out_size; (void)ws_size;
  const float* feat[2] = {(const float*)d_in[0], (const float*)d_in[1]};
  const float* xmat[2] = {(const float*)d_in[2], (const float*)d_in[3]};
  const int* esrc[2] = {(const int*)d_in[4], (const int*)d_in[6]};
  const int* edst[2] = {(const int*)d_in[5], (const int*)d_in[7]};
  const int* aseg[2] = {(const int*)d_in[8], (const int*)d_in[9]};

  struct P {
    const float *W_mlp, *b_mlp, *bn_g, *bn_b, *Wl0, *Wr0, *b0, *Wl1, *Wr1, *b1, *Wp, *bp;
  } prm[2];
  for (int p = 0; p < 2; p++) {
    int b = 10 + 12 * p;
    prm[p] = {(const float*)d_in[b + 0], (const float*)d_in[b + 1],
              (const float*)d_in[b + 2], (const float*)d_in[b + 3],
              (const float*)d_in[b + 4], (const float*)d_in[b + 5],
              (const float*)d_in[b + 6], (const float*)d_in[b + 7],
              (const float*)d_in[b + 8], (const float*)d_in[b + 9],
              (const float*)d_in[b + 10], (const float*)d_in[b + 11]};
  }

  char* w = (char*)d_ws;
  auto carve = [&](size_t bytes) -> char* {
    char* r = w;
    w += (bytes + 255) & ~(size_t)255;
    return r;
  };
  // ---- zeroed region (single memset) ----
  char* zbase = w;
  int* gcursor = (int*)carve(NSB * 4);
  int* cnt    = (int*)carve((size_t)2 * M_ROWS * 4);
  float* bnstat = (float*)carve(2 * 256 * 4);
  float* lossacc = (float*)carve(64 * 4);
  float* zerobuf = (float*)carve(256 * 4);
  float* yb   = (float*)carve((size_t)2 * M_ROWS * OUT_DIM * 4);
  size_t zbytes = (size_t)(w - zbase);
  // ---- non-zeroed ----
  u16* hb   = (u16*)carve((size_t)2 * N_NODES * HID * 2);
  u16* aggb = (u16*)carve((size_t)2 * N_NODES * HID * 2);
  u32* sbuf = (u32*)aggb;  // aliased: sbuf dead before first aggregate write
  float* dinv = (float*)carve((size_t)2 * N_NODES * 4);
  float* abc = (float*)carve(1024 * 4);  // a|c|nc|bias0p
  int* offs = (int*)carve((size_t)(2 * N_NODES + 1) * 4);
  u16* colu = (u16*)carve((size_t)2 * E_EDGES * 2);
  u16* BtAll = (u16*)carve((size_t)2 * 106496 * 2);

  const int TWO_N = 2 * N_NODES;

  EdgeArgs ea;
  for (int p = 0; p < 2; p++) { ea.src[p] = esrc[p]; ea.dst[p] = edst[p]; ea.seg[p] = aseg[p]; }

  CvtArgs ca;
  for (int p = 0; p < 2; p++) {
    ca.W[p * 6 + 0] = prm[p].W_mlp; ca.W[p * 6 + 1] = prm[p].Wl0;
    ca.W[p * 6 + 2] = prm[p].Wr0;   ca.W[p * 6 + 3] = prm[p].Wl1;
    ca.W[p * 6 + 4] = prm[p].Wr1;   ca.W[p * 6 + 5] = prm[p].Wp;
  }
  ca.Bt = BtAll;

  auto mkga = [&](int mode, int layer) {
    GArgs g{};
    for (int p = 0; p < 2; p++) {
      u16* hp = hb + (size_t)p * N_NODES * HID;
      const u16* btp = BtAll + (size_t)p * 106496;
      g.Cb[p] = hp;
      g.bnsum[p] = bnstat + p * 256;
      g.bnss[p] = bnstat + p * 256 + 128;
      g.seg[p] = aseg[p];
      g.cnt[p] = cnt + p * M_ROWS;
      g.y[p] = yb + (size_t)p * M_ROWS * OUT_DIM;
      if (mode == 0) {
        g.A1[p] = feat[p];
        g.Bt[p] = btp;
        g.bias[p] = prm[p].b_mlp;
      } else if (mode == 1) {
        g.A1[p] = hp;
        g.A2[p] = aggb + (size_t)p * N_NODES * HID;
        g.Bt[p] = btp + (layer ? 65536 : 32768);
        g.bias[p] = layer ? prm[p].b1 : (const float*)(abc + 768 + p * 128);
      } else {
        g.A1[p] = hp;
        g.Bt[p] = btp + 98304;
        g.bias[p] = prm[p].bp;
      }
    }
    return g;
  };

  const int GX = (N_NODES + 127) / 128;  // 391 blocks of 128 rows (4 waves x 32)

  hipMemsetAsync(zbase, 0, zbytes, stream);
  cvt_weightsA<<<(2 * 106496 + 255) / 256, 256, 0, stream>>>(ca);
  // edge partition + CSR build (runs while encode GEMM params prepared)
  part_edges<<<(2 * E_EDGES + 2047) / 2048, 256, 0, stream>>>(ea, sbuf, gcursor);
  build_csr<<<NSB, 1024, 0, stream>>>(sbuf, gcursor, offs, dinv, colu);
  cnt_count<<<(TWO_N + 255) / 256, 256, 0, stream>>>(ea, cnt);
  // encode (both panels) + BN stats; h stays PRE-BN (affine folded downstream)
  gemm_stream<128, 0, IN_DIM><<<dim3(GX, 2), 256, 0, stream>>>(mkga(0, 0), N_NODES);
  bn_final<<<1, 256, 0, stream>>>(bnstat, prm[0].bn_g, prm[0].bn_b,
                                  prm[1].bn_g, prm[1].bn_b, abc);
  cvt_fold<<<(65536 + 256 + 255) / 256, 256, 0, stream>>>(
      prm[0].Wl0, prm[0].Wr0, prm[1].Wl0, prm[1].Wr0, prm[0].b0, prm[1].b0,
      abc, BtAll);
  // SAGE layer 0 (raw h + BN-folded weights; deg==0 rows patched with nc)
  aggregate_bf16<<<(TWO_N * 64 + 255) / 256, 256, 0, stream>>>(
      hb, colu, offs, dinv, abc + 512, aggb);
  gemm_stream<128, 1, 2 * HID><<<dim3(GX, 2), 256, 0, stream>>>(mkga(1, 0), N_NODES);
  // SAGE layer 1 (in-place h; deg==0 rows -> 0)
  aggregate_bf16<<<(TWO_N * 64 + 255) / 256, 256, 0, stream>>>(
      hb, colu, offs, dinv, zerobuf, aggb);
  gemm_stream<128, 1, 2 * HID><<<dim3(GX, 2), 256, 0, stream>>>(mkga(1, 1), N_NODES);
  // projection + mean-pool
  gemm_stream<64, 2, HID><<<dim3(GX, 2), 256, 0, stream>>>(mkga(2, 0), N_NODES);
  mse_kernel<<<dim3(128, 2), 256, 0, stream>>>(yb, xmat[0], xmat[1], lossacc);
  finalize<<<1, 64, 0, stream>>>(lossacc, (float*)d_out);
}

// Round 2
// 349.289 us; speedup vs baseline: 1.1966x; 1.1966x over previous
//
#include <hip/hip_runtime.h>

#define N_NODES 50000
#define E_EDGES 800000
#define M_ROWS  12500
#define IN_DIM  256
#define HID     128
#define OUT_DIM 64
#define EPS     1e-5f
#define SLOPE   0.1f
#define NSB     25          // super-buckets of 4096 nodes over [0, 2N)
#define SB_CAP  (96 * 1024) // >> 64K avg +129 sigma; fixed inputs safe

typedef unsigned short u16;
typedef unsigned int u32;
typedef __attribute__((ext_vector_type(8))) short short8;
typedef __attribute__((ext_vector_type(4))) float f32x4;

__device__ __forceinline__ float leaky_f(float x) { return x >= 0.f ? x : SLOPE * x; }

__device__ __forceinline__ u16 f2bf(float f) {
  u32 x = __float_as_uint(f);
  return (u16)((x + 0x7fffu + ((x >> 16) & 1u)) >> 16);
}
__device__ __forceinline__ float bf2f(u16 u) { return __uint_as_float((u32)u << 16); }
__device__ __forceinline__ float bf2f_lo(u32 v) { return __uint_as_float(v << 16); }
__device__ __forceinline__ float bf2f_hi(u32 v) { return __uint_as_float(v & 0xffff0000u); }

struct GArgs {
  const void* A1[2];
  const void* A2[2];
  const u16* Bt[2];
  const float* bias[2];
  u16* Cb[2];
  float* bnsum[2];
  float* bnss[2];
  const int* seg[2];
  const int* cnt[2];
  float* y[2];
};

struct EdgeArgs {
  const int* src[2];
  const int* dst[2];
  const int* seg[2];
};

struct CvtArgs {
  const float* W[12];
  u16* Bt;
};

// ---------------------------------------------------------------------------
// One-latency-wall streaming MFMA GEMM. 512 threads = 8 waves; wave owns a
// 16-row x BN strip.
// Prologue: (1) issue B-staging loads (L2-resident Bt) into regs, (2) issue
// ALL A loads for the wave's 16 rows (8x short8 = full K) -- independent,
// back-to-back, (3) ds_write B to LDS (+8 pad -> 2-way = free), (4) ONE
// __syncthreads drains everything. Steady state: pure ds_read+MFMA, zero
// global loads, zero vmcnt stalls. This replaces the per-K-step memory
// round-trip that serialized both prior versions at ~1 TB/s.
// MODE 0 ENCODE: A1 = f32; C = bf16 leaky; BN col stats via LDS block-reduce.
// MODE 1 LAYER : A1,A2 = bf16 (K split 128+128); C = bf16 leaky (in-place
//                safe: waves only write rows they own; tail-clamp reads feed
//                never-stored acc rows).
// MODE 2 POOL  : A1 = bf16; no act; atomicAdd (v*w) into y[seg[row]][col].
// ---------------------------------------------------------------------------
template <int BN, int MODE, int KTOT>
__global__ __launch_bounds__(512, 2) void gemm_stream(GArgs ga, int nrows) {
  constexpr int NI = BN / 16;
  constexpr int KT = KTOT / 32;
  constexpr int LDK = KTOT + 8;                 // pad 8 u16 = 16B
  constexpr int BEL = BN * KTOT;                // B elements
  constexpr int SIT = BEL / (512 * 8);          // staging iters
  constexpr int KSH = (KTOT == 256) ? 8 : 7;
  __shared__ u16 Bs[BN * LDK];
  __shared__ float redS[(MODE == 0) ? 128 : 1];
  __shared__ float redQ[(MODE == 0) ? 128 : 1];

  const int pb = blockIdx.y;
  const int t = threadIdx.x;
  const int w = t >> 6, lane = t & 63;
  const int laneM = lane & 15, kg = lane >> 4;
  const int r0 = blockIdx.x * 128 + w * 16;

  const u16* Bt = ga.Bt[pb];
  const float* bias = ga.bias[pb];

  int ra = r0 + laneM;
  if (ra >= nrows) ra = nrows - 1;

  // ---- (1) B-staging loads first (oldest in vmcnt queue) ----
  short8 sreg[SIT];
#pragma unroll
  for (int si = 0; si < SIT; si++)
    sreg[si] = *(const short8*)(Bt + si * 4096 + t * 8);

  // ---- (2) full-K A prefetch: independent HBM loads, one latency wall ----
  float4 pf[(MODE == 0) ? 2 * KT : 1];
  short8 af[(MODE == 0) ? 1 : KT];
  if constexpr (MODE == 0) {
    const float* A = (const float*)ga.A1[pb] + (size_t)ra * KTOT + kg * 8;
#pragma unroll
    for (int kt = 0; kt < KT; kt++) {
      pf[2 * kt] = *(const float4*)(A + kt * 32);
      pf[2 * kt + 1] = *(const float4*)(A + kt * 32 + 4);
    }
  } else if constexpr (MODE == 1) {
    const u16* A1 = (const u16*)ga.A1[pb] + (size_t)ra * HID + kg * 8;
    const u16* A2 = (const u16*)ga.A2[pb] + (size_t)ra * HID + kg * 8;
#pragma unroll
    for (int kt = 0; kt < KT / 2; kt++) af[kt] = *(const short8*)(A1 + kt * 32);
#pragma unroll
    for (int kt = 0; kt < KT / 2; kt++)
      af[KT / 2 + kt] = *(const short8*)(A2 + kt * 32);
  } else {
    const u16* A1 = (const u16*)ga.A1[pb] + (size_t)ra * HID + kg * 8;
#pragma unroll
    for (int kt = 0; kt < KT; kt++) af[kt] = *(const short8*)(A1 + kt * 32);
  }

  // ---- (3) write staged B to padded LDS ----
  if constexpr (MODE == 0) {
    if (t < 128) { redS[t] = 0.f; redQ[t] = 0.f; }
  }
#pragma unroll
  for (int si = 0; si < SIT; si++) {
    int i = si * 4096 + t * 8;
    int n = i >> KSH;
    int k = i & (KTOT - 1);
    *(short8*)&Bs[n * LDK + k] = sreg[si];
  }
  __syncthreads();

  // ---- steady state: pure LDS + MFMA ----
  f32x4 acc[NI];
#pragma unroll
  for (int ni = 0; ni < NI; ni++) acc[ni] = (f32x4){0.f, 0.f, 0.f, 0.f};

#pragma unroll
  for (int kt = 0; kt < KT; kt++) {
    const int k0 = kt * 32 + kg * 8;
    short8 a;
    if constexpr (MODE == 0) {
      float4 v0 = pf[2 * kt], v1 = pf[2 * kt + 1];
      a[0] = (short)f2bf(v0.x); a[1] = (short)f2bf(v0.y);
      a[2] = (short)f2bf(v0.z); a[3] = (short)f2bf(v0.w);
      a[4] = (short)f2bf(v1.x); a[5] = (short)f2bf(v1.y);
      a[6] = (short)f2bf(v1.z); a[7] = (short)f2bf(v1.w);
    } else {
      a = af[kt];
    }
#pragma unroll
    for (int ni = 0; ni < NI; ni++) {
      short8 b = *(const short8*)&Bs[(ni * 16 + laneM) * LDK + k0];
      acc[ni] = __builtin_amdgcn_mfma_f32_16x16x32_bf16(a, b, acc[ni], 0, 0, 0);
    }
  }

  // ---- epilogue ----
  float bcol[NI];
#pragma unroll
  for (int ni = 0; ni < NI; ni++) bcol[ni] = bias[ni * 16 + laneM];

  float ssum[NI], ssq[NI];
#pragma unroll
  for (int ni = 0; ni < NI; ni++) { ssum[ni] = 0.f; ssq[ni] = 0.f; }

#pragma unroll
  for (int r = 0; r < 4; r++) {
    int gr = r0 + kg * 4 + r;
    if (gr >= nrows) continue;
    float pw = 0.f;
    int sI = 0;
    if constexpr (MODE == 2) {
      sI = ga.seg[pb][gr];
      int cv = ga.cnt[pb][sI];
      pw = 1.f / (float)(cv > 1 ? cv : 1);
    }
#pragma unroll
    for (int ni = 0; ni < NI; ni++) {
      int col = ni * 16 + laneM;
      float v = acc[ni][r] + bcol[ni];
      if constexpr (MODE == 0) {
        v = leaky_f(v);
        ga.Cb[pb][(size_t)gr * BN + col] = f2bf(v);
        ssum[ni] += v;
        ssq[ni] += v * v;
      } else if constexpr (MODE == 1) {
        v = leaky_f(v);
        ga.Cb[pb][(size_t)gr * BN + col] = f2bf(v);
      } else {
        atomicAdd(&ga.y[pb][(size_t)sI * OUT_DIM + col], v * pw);
      }
    }
  }

  if constexpr (MODE == 0) {
#pragma unroll
    for (int ni = 0; ni < NI; ni++) {
      float a = ssum[ni], b = ssq[ni];
      a += __shfl_xor(a, 16); a += __shfl_xor(a, 32);
      b += __shfl_xor(b, 16); b += __shfl_xor(b, 32);
      if (kg == 0) {
        atomicAdd(&redS[ni * 16 + laneM], a);
        atomicAdd(&redQ[ni * 16 + laneM], b);
      }
    }
    __syncthreads();
    if (t < 128) {
      atomicAdd(&ga.bnsum[pb][t], redS[t]);
      atomicAdd(&ga.bnss[pb][t], redQ[t]);
    }
  }
}

// Weights -> bf16 transposed Bt[n][k]; SKIPS Bt0 (folded later with BN affine).
__global__ __launch_bounds__(256) void cvt_weightsA(CvtArgs a) {
  int i = blockIdx.x * 256 + threadIdx.x;
  if (i >= 2 * 106496) return;
  int p = i >= 106496;
  int j = i - p * 106496;
  const float* const* W = a.W + p * 6;
  u16* out = a.Bt + (size_t)p * 106496;
  if (j < 32768) {
    int n = j >> 8, k = j & 255;
    out[j] = f2bf(W[0][k * 128 + n]);
  } else if (j < 65536) {
    return;
  } else if (j < 98304) {
    int q = j - 65536, n = q >> 8, k = q & 255;
    out[j] = f2bf(k < 128 ? W[3][k * 128 + n] : W[4][(k - 128) * 128 + n]);
  } else {
    int q = j - 98304, n = q >> 7, k = q & 127;
    out[j] = f2bf(W[5][k * 64 + n]);
  }
}

// abc layout: a[256] | c[256] | nc[256] | bias0p[256]
__global__ void bn_final(const float* __restrict__ bnstat,
                         const float* __restrict__ g0, const float* __restrict__ b0,
                         const float* __restrict__ g1, const float* __restrict__ b1,
                         float* __restrict__ abc) {
  int t = threadIdx.x;  // 256
  int p = t >> 7, cix = t & 127;
  const float* bs = bnstat + p * 256;
  float mu = bs[cix] * (1.f / N_NODES);
  float var = bs[128 + cix] * (1.f / N_NODES) - mu * mu;
  float rs = rsqrtf(var + EPS);
  const float* g = p ? g1 : g0;
  const float* b = p ? b1 : b0;
  float av = g[cix] * rs;
  float cv = b[cix] - mu * av;
  abc[t] = av;
  abc[256 + t] = cv;
  abc[512 + t] = (av != 0.f) ? (-cv / av) : 0.f;
}

// Fold BN affine into layer-0 weights.
__global__ __launch_bounds__(256) void cvt_fold(
    const float* __restrict__ Wl0_0, const float* __restrict__ Wr0_0,
    const float* __restrict__ Wl0_1, const float* __restrict__ Wr0_1,
    const float* __restrict__ b0_0, const float* __restrict__ b0_1,
    float* __restrict__ abc, u16* __restrict__ BtAll) {
  int i = blockIdx.x * 256 + threadIdx.x;
  if (i < 65536) {
    int p = i >> 15, q = i & 32767;
    int n = q >> 8, k = q & 255;
    const float* Wl = p ? Wl0_1 : Wl0_0;
    const float* Wr = p ? Wr0_1 : Wr0_0;
    float wv = (k < 128) ? Wl[k * 128 + n] : Wr[(k - 128) * 128 + n];
    float av = abc[p * 128 + (k & 127)];
    BtAll[(size_t)p * 106496 + 32768 + q] = f2bf(wv * av);
  } else if (i < 65536 + 256) {
    int j = i - 65536;
    int p = j >> 7, n = j & 127;
    const float* Wl = p ? Wl0_1 : Wl0_0;
    const float* Wr = p ? Wr0_1 : Wr0_0;
    const float* c = abc + 256 + p * 128;
    float s = (p ? b0_1 : b0_0)[n];
    for (int k = 0; k < 128; k++) s += c[k] * (Wl[k * 128 + n] + Wr[k * 128 + n]);
    abc[768 + j] = s;
  }
}

// pooling counts
__global__ void cnt_count(EdgeArgs ea, int* __restrict__ cnt) {
  int i = blockIdx.x * blockDim.x + threadIdx.x;
  if (i < 2 * N_NODES) {
    int p = i >= N_NODES;
    int k = i - p * N_NODES;
    atomicAdd(&cnt[p * M_ROWS + ea.seg[p][k]], 1);
  }
}

// --------- Phase A: partition edges into NSB super-buckets ------------------
// packed: dst_local(12b) << 17 | src(17b). Tile = 2048 edges, block-local
// counting sort, contiguous chunk copy-out (full-line single-CU writes).
__global__ __launch_bounds__(256) void part_edges(EdgeArgs ea, u32* __restrict__ sbuf,
                                                  int* __restrict__ gcursor) {
  __shared__ u32 lpack[2048];
  __shared__ int hist[NSB], base[NSB], gbase[NSB], lofs[NSB];
  int t = threadIdx.x;
  int e0 = blockIdx.x * 2048;
  if (t < NSB) hist[t] = 0;
  __syncthreads();
  u32 myp[8];
  int myb[8];
#pragma unroll
  for (int q = 0; q < 8; q++) {
    int i = e0 + q * 256 + t;
    int b = -1;
    u32 pk = 0;
    if (i < 2 * E_EDGES) {
      int p = i >= E_EDGES;
      int j = i - p * E_EDGES;
      int d = p * N_NODES + ea.dst[p][j];
      int s = ea.src[p][j];
      b = d >> 12;
      pk = ((u32)(d & 4095) << 17) | (u32)s;
      atomicAdd(&hist[b], 1);
    }
    myb[q] = b;
    myp[q] = pk;
  }
  __syncthreads();
  if (t == 0) {
    int acc = 0;
    for (int b = 0; b < NSB; b++) { base[b] = acc; acc += hist[b]; }
  }
  __syncthreads();
  if (t < NSB) {
    lofs[t] = 0;
    gbase[t] = atomicAdd(&gcursor[t], hist[t]);
  }
  __syncthreads();
#pragma unroll
  for (int q = 0; q < 8; q++) {
    if (myb[q] >= 0) {
      int pos = atomicAdd(&lofs[myb[q]], 1);
      lpack[base[myb[q]] + pos] = myp[q];
    }
  }
  __syncthreads();
  for (int b = 0; b < NSB; b++) {
    int n = hist[b], lb = base[b], gb = gbase[b];
    for (int k = t; k < n; k += 256)
      sbuf[(size_t)b * SB_CAP + gb + k] = lpack[lb + k];
  }
}

// --------- Phase B: per-super-bucket CSR build (one block per bucket) -------
__global__ __launch_bounds__(1024) void build_csr(
    const u32* __restrict__ sbuf, const int* __restrict__ gtot,
    int* __restrict__ offs, float* __restrict__ dinv, u16* __restrict__ colu) {
  __shared__ int ldeg[4096];
  __shared__ int lcur[4096];
  __shared__ int wsum[16];
  __shared__ int sb_tot[NSB];
  int b = blockIdx.x, t = threadIdx.x;
  if (t < NSB) sb_tot[t] = gtot[t];
  for (int k = t; k < 4096; k += 1024) ldeg[k] = 0;
  __syncthreads();
  int edge_base = 0;
  for (int i = 0; i < b; i++) edge_base += sb_tot[i];
  int cnt = sb_tot[b];
  int node0 = b << 12;
  int nend = 2 * N_NODES - node0;
  if (nend > 4096) nend = 4096;
  const u32* me = sbuf + (size_t)b * SB_CAP;
  for (int k = t; k < cnt; k += 1024) atomicAdd(&ldeg[me[k] >> 17], 1);
  __syncthreads();
  // block scan over 4096 (each thread: 4 consecutive)
  int d0 = ldeg[4 * t], d1 = ldeg[4 * t + 1], d2 = ldeg[4 * t + 2], d3 = ldeg[4 * t + 3];
  int ts = d0 + d1 + d2 + d3;
  int lane = t & 63, wid = t >> 6;
  int incl = ts;
#pragma unroll
  for (int off = 1; off < 64; off <<= 1) {
    int u = __shfl_up(incl, off, 64);
    if (lane >= off) incl += u;
  }
  if (lane == 63) wsum[wid] = incl;
  __syncthreads();
  if (t < 64) {
    int v = (t < 16) ? wsum[t] : 0;
    int iv = v;
#pragma unroll
    for (int off = 1; off < 16; off <<= 1) {
      int u = __shfl_up(iv, off, 64);
      if (t >= off) iv += u;
    }
    if (t < 16) wsum[t] = iv - v;
  }
  __syncthreads();
  int ex = wsum[wid] + incl - ts;
  int e1 = ex + d0, e2 = e1 + d1, e3 = e2 + d2;
  int n0 = node0 + 4 * t;
  int lexp[4] = {ex, e1, e2, e3};
  int ldg[4] = {d0, d1, d2, d3};
#pragma unroll
  for (int k = 0; k < 4; k++) {
    if (4 * t + k < nend) {
      offs[n0 + k] = edge_base + lexp[k];
      dinv[n0 + k] = ldg[k] > 0 ? 1.f / (float)ldg[k] : -1.f;
    }
    lcur[4 * t + k] = lexp[k];
  }
  __syncthreads();
  for (int k = t; k < cnt; k += 1024) {
    u32 v = me[k];
    int pos = atomicAdd(&lcur[v >> 17], 1);
    colu[edge_base + pos] = (u16)(v & 0x1FFFFu);
  }
  if (b == 0 && t == 0) offs[2 * N_NODES] = 2 * E_EDGES;
}

// --------- mean-aggregate: 1 wave/node, lanes split into 2 edge-halves ------
// lane<32: edge j, lane>=32: edge j+1; each lane loads 8B (4 bf16 cols).
// dinv<0 marks deg==0 -> nc[panel][col] (BN-fold patch or zeros).
__global__ __launch_bounds__(256) void aggregate_bf16(
    const u16* __restrict__ h, const u16* __restrict__ colu,
    const int* __restrict__ offs, const float* __restrict__ dinv,
    const float* __restrict__ nc, u16* __restrict__ agg) {
  int gw = (blockIdx.x * 256 + threadIdx.x) >> 6;
  int lane = threadIdx.x & 63;
  if (gw >= 2 * N_NODES) return;
  int panel = gw >= N_NODES;
  const uint2* hp = (const uint2*)(h + (size_t)panel * N_NODES * 128);
  int half = lane >> 5, li = lane & 31;
  int s = offs[gw], e = offs[gw + 1];
  float a0 = 0.f, a1 = 0.f, a2 = 0.f, a3 = 0.f;
  int j = s;
  for (; j + 8 <= e; j += 8) {
    int c0 = colu[j + half], c1 = colu[j + 2 + half];
    int c2 = colu[j + 4 + half], c3 = colu[j + 6 + half];
    uint2 v0 = hp[(size_t)c0 * 32 + li];
    uint2 v1 = hp[(size_t)c1 * 32 + li];
    uint2 v2 = hp[(size_t)c2 * 32 + li];
    uint2 v3 = hp[(size_t)c3 * 32 + li];
    a0 += (bf2f_lo(v0.x) + bf2f_lo(v1.x)) + (bf2f_lo(v2.x) + bf2f_lo(v3.x));
    a1 += (bf2f_hi(v0.x) + bf2f_hi(v1.x)) + (bf2f_hi(v2.x) + bf2f_hi(v3.x));
    a2 += (bf2f_lo(v0.y) + bf2f_lo(v1.y)) + (bf2f_lo(v2.y) + bf2f_lo(v3.y));
    a3 += (bf2f_hi(v0.y) + bf2f_hi(v1.y)) + (bf2f_hi(v2.y) + bf2f_hi(v3.y));
  }
  for (; j + 2 <= e; j += 2) {
    int c = colu[j + half];
    uint2 v = hp[(size_t)c * 32 + li];
    a0 += bf2f_lo(v.x);
    a1 += bf2f_hi(v.x);
    a2 += bf2f_lo(v.y);
    a3 += bf2f_hi(v.y);
  }
  if (j < e) {
    int c = colu[j];
    uint2 v = hp[(size_t)c * 32 + li];
    if (half == 0) {
      a0 += bf2f_lo(v.x);
      a1 += bf2f_hi(v.x);
      a2 += bf2f_lo(v.y);
      a3 += bf2f_hi(v.y);
    }
  }
  a0 += __shfl_xor(a0, 32);
  a1 += __shfl_xor(a1, 32);
  a2 += __shfl_xor(a2, 32);
  a3 += __shfl_xor(a3, 32);
  if (half == 0) {
    float di = dinv[gw];
    float o0, o1, o2, o3;
    if (di < 0.f) {
      const float* np = nc + panel * 128 + li * 4;
      o0 = np[0]; o1 = np[1]; o2 = np[2]; o3 = np[3];
    } else {
      o0 = a0 * di; o1 = a1 * di; o2 = a2 * di; o3 = a3 * di;
    }
    uint2 o;
    o.x = ((u32)f2bf(o1) << 16) | (u32)f2bf(o0);
    o.y = ((u32)f2bf(o3) << 16) | (u32)f2bf(o2);
    ((uint2*)agg)[(size_t)gw * 32 + li] = o;
  }
}

__global__ __launch_bounds__(256) void mse_kernel(const float* __restrict__ yb,
                                                  const float* __restrict__ x0,
                                                  const float* __restrict__ x1,
                                                  float* __restrict__ acc) {
  __shared__ float ls[256];
  int pb = blockIdx.y;
  const float* y = yb + (size_t)pb * M_ROWS * OUT_DIM;
  const float* x = pb ? x1 : x0;
  float s = 0.f;
  for (int i = blockIdx.x * 256 + threadIdx.x; i < M_ROWS * OUT_DIM; i += gridDim.x * 256) {
    float d = y[i] - x[i];
    s += d * d;
  }
  ls[threadIdx.x] = s;
  __syncthreads();
  for (int o = 128; o > 0; o >>= 1) {
    if (threadIdx.x < o) ls[threadIdx.x] += ls[threadIdx.x + o];
    __syncthreads();
  }
  if (threadIdx.x == 0) atomicAdd(&acc[pb], ls[0]);
}

__global__ void finalize(const float* __restrict__ acc, float* __restrict__ out) {
  int t = threadIdx.x;
  if (t < 2) out[t] = acc[t] * (1.f / (float)(M_ROWS * OUT_DIM));
}

// ---------------------------------------------------------------------------
extern "C" void kernel_launch(void* const* d_in, const int* in_sizes, int n_in,
                              void* d_out, int out_size, void* d_ws, size_t ws_size,
                              hipStream_t stream) {
  (void)in_sizes; (void)n_in; (void)out_size; (void)ws_size;
  const float* feat[2] = {(const float*)d_in[0], (const float*)d_in[1]};
  const float* xmat[2] = {(const float*)d_in[2], (const float*)d_in[3]};
  const int* esrc[2] = {(const int*)d_in[4], (const int*)d_in[6]};
  const int* edst[2] = {(const int*)d_in[5], (const int*)d_in[7]};
  const int* aseg[2] = {(const int*)d_in[8], (const int*)d_in[9]};

  struct P {
    const float *W_mlp, *b_mlp, *bn_g, *bn_b, *Wl0, *Wr0, *b0, *Wl1, *Wr1, *b1, *Wp, *bp;
  } prm[2];
  for (int p = 0; p < 2; p++) {
    int b = 10 + 12 * p;
    prm[p] = {(const float*)d_in[b + 0], (const float*)d_in[b + 1],
              (const float*)d_in[b + 2], (const float*)d_in[b + 3],
              (const float*)d_in[b + 4], (const float*)d_in[b + 5],
              (const float*)d_in[b + 6], (const float*)d_in[b + 7],
              (const float*)d_in[b + 8], (const float*)d_in[b + 9],
              (const float*)d_in[b + 10], (const float*)d_in[b + 11]};
  }

  char* w = (char*)d_ws;
  auto carve = [&](size_t bytes) -> char* {
    char* r = w;
    w += (bytes + 255) & ~(size_t)255;
    return r;
  };
  // ---- zeroed region (single memset) ----
  char* zbase = w;
  int* gcursor = (int*)carve(NSB * 4);
  int* cnt    = (int*)carve((size_t)2 * M_ROWS * 4);
  float* bnstat = (float*)carve(2 * 256 * 4);
  float* lossacc = (float*)carve(64 * 4);
  float* zerobuf = (float*)carve(256 * 4);
  float* yb   = (float*)carve((size_t)2 * M_ROWS * OUT_DIM * 4);
  size_t zbytes = (size_t)(w - zbase);
  // ---- non-zeroed ----
  u16* hb   = (u16*)carve((size_t)2 * N_NODES * HID * 2);
  u16* aggb = (u16*)carve((size_t)2 * N_NODES * HID * 2);
  u32* sbuf = (u32*)aggb;  // aliased: sbuf dead before first aggregate write
  float* dinv = (float*)carve((size_t)2 * N_NODES * 4);
  float* abc = (float*)carve(1024 * 4);  // a|c|nc|bias0p
  int* offs = (int*)carve((size_t)(2 * N_NODES + 1) * 4);
  u16* colu = (u16*)carve((size_t)2 * E_EDGES * 2);
  u16* BtAll = (u16*)carve((size_t)2 * 106496 * 2);

  const int TWO_N = 2 * N_NODES;

  EdgeArgs ea;
  for (int p = 0; p < 2; p++) { ea.src[p] = esrc[p]; ea.dst[p] = edst[p]; ea.seg[p] = aseg[p]; }

  CvtArgs ca;
  for (int p = 0; p < 2; p++) {
    ca.W[p * 6 + 0] = prm[p].W_mlp; ca.W[p * 6 + 1] = prm[p].Wl0;
    ca.W[p * 6 + 2] = prm[p].Wr0;   ca.W[p * 6 + 3] = prm[p].Wl1;
    ca.W[p * 6 + 4] = prm[p].Wr1;   ca.W[p * 6 + 5] = prm[p].Wp;
  }
  ca.Bt = BtAll;

  auto mkga = [&](int mode, int layer) {
    GArgs g{};
    for (int p = 0; p < 2; p++) {
      u16* hp = hb + (size_t)p * N_NODES * HID;
      const u16* btp = BtAll + (size_t)p * 106496;
      g.Cb[p] = hp;
      g.bnsum[p] = bnstat + p * 256;
      g.bnss[p] = bnstat + p * 256 + 128;
      g.seg[p] = aseg[p];
      g.cnt[p] = cnt + p * M_ROWS;
      g.y[p] = yb + (size_t)p * M_ROWS * OUT_DIM;
      if (mode == 0) {
        g.A1[p] = feat[p];
        g.Bt[p] = btp;
        g.bias[p] = prm[p].b_mlp;
      } else if (mode == 1) {
        g.A1[p] = hp;
        g.A2[p] = aggb + (size_t)p * N_NODES * HID;
        g.Bt[p] = btp + (layer ? 65536 : 32768);
        g.bias[p] = layer ? prm[p].b1 : (const float*)(abc + 768 + p * 128);
      } else {
        g.A1[p] = hp;
        g.Bt[p] = btp + 98304;
        g.bias[p] = prm[p].bp;
      }
    }
    return g;
  };

  const int GX = (N_NODES + 127) / 128;  // 391 blocks of 128 rows (8 waves x 16)

  hipMemsetAsync(zbase, 0, zbytes, stream);
  cvt_weightsA<<<(2 * 106496 + 255) / 256, 256, 0, stream>>>(ca);
  // edge partition + CSR build (runs while encode GEMM params prepared)
  part_edges<<<(2 * E_EDGES + 2047) / 2048, 256, 0, stream>>>(ea, sbuf, gcursor);
  build_csr<<<NSB, 1024, 0, stream>>>(sbuf, gcursor, offs, dinv, colu);
  cnt_count<<<(TWO_N + 255) / 256, 256, 0, stream>>>(ea, cnt);
  // encode (both panels) + BN stats; h stays PRE-BN (affine folded downstream)
  gemm_stream<128, 0, IN_DIM><<<dim3(GX, 2), 512, 0, stream>>>(mkga(0, 0), N_NODES);
  bn_final<<<1, 256, 0, stream>>>(bnstat, prm[0].bn_g, prm[0].bn_b,
                                  prm[1].bn_g, prm[1].bn_b, abc);
  cvt_fold<<<(65536 + 256 + 255) / 256, 256, 0, stream>>>(
      prm[0].Wl0, prm[0].Wr0, prm[1].Wl0, prm[1].Wr0, prm[0].b0, prm[1].b0,
      abc, BtAll);
  // SAGE layer 0 (raw h + BN-folded weights; deg==0 rows patched with nc)
  aggregate_bf16<<<(TWO_N * 64 + 255) / 256, 256, 0, stream>>>(
      hb, colu, offs, dinv, abc + 512, aggb);
  gemm_stream<128, 1, 2 * HID><<<dim3(GX, 2), 512, 0, stream>>>(mkga(1, 0), N_NODES);
  // SAGE layer 1 (in-place h; deg==0 rows -> 0)
  aggregate_bf16<<<(TWO_N * 64 + 255) / 256, 256, 0, stream>>>(
      hb, colu, offs, dinv, zerobuf, aggb);
  gemm_stream<128, 1, 2 * HID><<<dim3(GX, 2), 512, 0, stream>>>(mkga(1, 1), N_NODES);
  // projection + mean-pool
  gemm_stream<64, 2, HID><<<dim3(GX, 2), 512, 0, stream>>>(mkga(2, 0), N_NODES);
  mse_kernel<<<dim3(128, 2), 256, 0, stream>>>(yb, xmat[0], xmat[1], lossacc);
  finalize<<<1, 64, 0, stream>>>(lossacc, (float*)d_out);
}

// Round 3
// 338.459 us; speedup vs baseline: 1.2349x; 1.0320x over previous
//
#include <hip/hip_runtime.h>

#define N_NODES 50000
#define E_EDGES 800000
#define M_ROWS  12500
#define IN_DIM  256
#define HID     128
#define OUT_DIM 64
#define EPS     1e-5f
#define SLOPE   0.1f
#define NSB     25          // super-buckets of 4096 nodes over [0, 2N)
#define SB_CAP  (96 * 1024) // >> 64K avg +129 sigma; fixed inputs safe

typedef unsigned short u16;
typedef unsigned int u32;
typedef __attribute__((ext_vector_type(8))) short short8;
typedef __attribute__((ext_vector_type(4))) float f32x4;

__device__ __forceinline__ float leaky_f(float x) { return x >= 0.f ? x : SLOPE * x; }

__device__ __forceinline__ u16 f2bf(float f) {
  u32 x = __float_as_uint(f);
  return (u16)((x + 0x7fffu + ((x >> 16) & 1u)) >> 16);
}
__device__ __forceinline__ float bf2f(u16 u) { return __uint_as_float((u32)u << 16); }
__device__ __forceinline__ float bf2f_lo(u32 v) { return __uint_as_float(v << 16); }
__device__ __forceinline__ float bf2f_hi(u32 v) { return __uint_as_float(v & 0xffff0000u); }

struct GArgs {
  const void* A1[2];
  const void* A2[2];
  const u16* Bt[2];
  const float* bias[2];
  u16* Cb[2];
  float* bnsum[2];
  float* bnss[2];
  const int* seg[2];
  const int* cnt[2];
  float* y[2];
};

struct EdgeArgs {
  const int* src[2];
  const int* dst[2];
  const int* seg[2];
};

struct CvtArgs {
  const float* W[12];
  u16* Bt;
};

// ---------------------------------------------------------------------------
// One-latency-wall streaming MFMA GEMM. 512 threads = 8 waves; wave owns a
// 16-row x BN strip. Prologue: B-staging loads -> all A loads (full K) ->
// ds_write B -> ONE __syncthreads. Steady state: pure ds_read+MFMA.
// MODE 0 ENCODE: A1 = f32; C = bf16 leaky; BN col stats via LDS block-reduce.
// MODE 1 LAYER : A1,A2 = bf16 (K split 128+128); C = bf16 leaky (in-place
//                safe: waves only write rows they own).
// MODE 2 POOL  : A1 = bf16; no act; atomicAdd (v*w) into y[seg[row]][col].
// ---------------------------------------------------------------------------
template <int BN, int MODE, int KTOT>
__global__ __launch_bounds__(512, 2) void gemm_stream(GArgs ga, int nrows) {
  constexpr int NI = BN / 16;
  constexpr int KT = KTOT / 32;
  constexpr int LDK = KTOT + 8;                 // pad 8 u16 = 16B
  constexpr int BEL = BN * KTOT;                // B elements
  constexpr int SIT = BEL / (512 * 8);          // staging iters
  constexpr int KSH = (KTOT == 256) ? 8 : 7;
  __shared__ u16 Bs[BN * LDK];
  __shared__ float redS[(MODE == 0) ? 128 : 1];
  __shared__ float redQ[(MODE == 0) ? 128 : 1];

  const int pb = blockIdx.y;
  const int t = threadIdx.x;
  const int w = t >> 6, lane = t & 63;
  const int laneM = lane & 15, kg = lane >> 4;
  const int r0 = blockIdx.x * 128 + w * 16;

  const u16* Bt = ga.Bt[pb];
  const float* bias = ga.bias[pb];

  int ra = r0 + laneM;
  if (ra >= nrows) ra = nrows - 1;

  // ---- (1) B-staging loads first (oldest in vmcnt queue) ----
  short8 sreg[SIT];
#pragma unroll
  for (int si = 0; si < SIT; si++)
    sreg[si] = *(const short8*)(Bt + si * 4096 + t * 8);

  // ---- (2) full-K A prefetch: independent HBM loads, one latency wall ----
  float4 pf[(MODE == 0) ? 2 * KT : 1];
  short8 af[(MODE == 0) ? 1 : KT];
  if constexpr (MODE == 0) {
    const float* A = (const float*)ga.A1[pb] + (size_t)ra * KTOT + kg * 8;
#pragma unroll
    for (int kt = 0; kt < KT; kt++) {
      pf[2 * kt] = *(const float4*)(A + kt * 32);
      pf[2 * kt + 1] = *(const float4*)(A + kt * 32 + 4);
    }
  } else if constexpr (MODE == 1) {
    const u16* A1 = (const u16*)ga.A1[pb] + (size_t)ra * HID + kg * 8;
    const u16* A2 = (const u16*)ga.A2[pb] + (size_t)ra * HID + kg * 8;
#pragma unroll
    for (int kt = 0; kt < KT / 2; kt++) af[kt] = *(const short8*)(A1 + kt * 32);
#pragma unroll
    for (int kt = 0; kt < KT / 2; kt++)
      af[KT / 2 + kt] = *(const short8*)(A2 + kt * 32);
  } else {
    const u16* A1 = (const u16*)ga.A1[pb] + (size_t)ra * HID + kg * 8;
#pragma unroll
    for (int kt = 0; kt < KT; kt++) af[kt] = *(const short8*)(A1 + kt * 32);
  }

  // ---- (3) write staged B to padded LDS ----
  if constexpr (MODE == 0) {
    if (t < 128) { redS[t] = 0.f; redQ[t] = 0.f; }
  }
#pragma unroll
  for (int si = 0; si < SIT; si++) {
    int i = si * 4096 + t * 8;
    int n = i >> KSH;
    int k = i & (KTOT - 1);
    *(short8*)&Bs[n * LDK + k] = sreg[si];
  }
  __syncthreads();

  // ---- steady state: pure LDS + MFMA ----
  f32x4 acc[NI];
#pragma unroll
  for (int ni = 0; ni < NI; ni++) acc[ni] = (f32x4){0.f, 0.f, 0.f, 0.f};

#pragma unroll
  for (int kt = 0; kt < KT; kt++) {
    const int k0 = kt * 32 + kg * 8;
    short8 a;
    if constexpr (MODE == 0) {
      float4 v0 = pf[2 * kt], v1 = pf[2 * kt + 1];
      a[0] = (short)f2bf(v0.x); a[1] = (short)f2bf(v0.y);
      a[2] = (short)f2bf(v0.z); a[3] = (short)f2bf(v0.w);
      a[4] = (short)f2bf(v1.x); a[5] = (short)f2bf(v1.y);
      a[6] = (short)f2bf(v1.z); a[7] = (short)f2bf(v1.w);
    } else {
      a = af[kt];
    }
#pragma unroll
    for (int ni = 0; ni < NI; ni++) {
      short8 b = *(const short8*)&Bs[(ni * 16 + laneM) * LDK + k0];
      acc[ni] = __builtin_amdgcn_mfma_f32_16x16x32_bf16(a, b, acc[ni], 0, 0, 0);
    }
  }

  // ---- epilogue ----
  float bcol[NI];
#pragma unroll
  for (int ni = 0; ni < NI; ni++) bcol[ni] = bias[ni * 16 + laneM];

  float ssum[NI], ssq[NI];
#pragma unroll
  for (int ni = 0; ni < NI; ni++) { ssum[ni] = 0.f; ssq[ni] = 0.f; }

#pragma unroll
  for (int r = 0; r < 4; r++) {
    int gr = r0 + kg * 4 + r;
    if (gr >= nrows) continue;
    float pw = 0.f;
    int sI = 0;
    if constexpr (MODE == 2) {
      sI = ga.seg[pb][gr];
      int cv = ga.cnt[pb][sI];
      pw = 1.f / (float)(cv > 1 ? cv : 1);
    }
#pragma unroll
    for (int ni = 0; ni < NI; ni++) {
      int col = ni * 16 + laneM;
      float v = acc[ni][r] + bcol[ni];
      if constexpr (MODE == 0) {
        v = leaky_f(v);
        ga.Cb[pb][(size_t)gr * BN + col] = f2bf(v);
        ssum[ni] += v;
        ssq[ni] += v * v;
      } else if constexpr (MODE == 1) {
        v = leaky_f(v);
        ga.Cb[pb][(size_t)gr * BN + col] = f2bf(v);
      } else {
        atomicAdd(&ga.y[pb][(size_t)sI * OUT_DIM + col], v * pw);
      }
    }
  }

  if constexpr (MODE == 0) {
#pragma unroll
    for (int ni = 0; ni < NI; ni++) {
      float a = ssum[ni], b = ssq[ni];
      a += __shfl_xor(a, 16); a += __shfl_xor(a, 32);
      b += __shfl_xor(b, 16); b += __shfl_xor(b, 32);
      if (kg == 0) {
        atomicAdd(&redS[ni * 16 + laneM], a);
        atomicAdd(&redQ[ni * 16 + laneM], b);
      }
    }
    __syncthreads();
    if (t < 128) {
      atomicAdd(&ga.bnsum[pb][t], redS[t]);
      atomicAdd(&ga.bnss[pb][t], redQ[t]);
    }
  }
}

// Weights -> bf16 transposed Bt[n][k]; SKIPS Bt0 (folded later with BN affine).
__global__ __launch_bounds__(256) void cvt_weightsA(CvtArgs a) {
  int i = blockIdx.x * 256 + threadIdx.x;
  if (i >= 2 * 106496) return;
  int p = i >= 106496;
  int j = i - p * 106496;
  const float* const* W = a.W + p * 6;
  u16* out = a.Bt + (size_t)p * 106496;
  if (j < 32768) {
    int n = j >> 8, k = j & 255;
    out[j] = f2bf(W[0][k * 128 + n]);
  } else if (j < 65536) {
    return;
  } else if (j < 98304) {
    int q = j - 65536, n = q >> 8, k = q & 255;
    out[j] = f2bf(k < 128 ? W[3][k * 128 + n] : W[4][(k - 128) * 128 + n]);
  } else {
    int q = j - 98304, n = q >> 7, k = q & 127;
    out[j] = f2bf(W[5][k * 64 + n]);
  }
}

// abc layout: a[256] | c[256] | nc[256] | bias0p[256]
__global__ void bn_final(const float* __restrict__ bnstat,
                         const float* __restrict__ g0, const float* __restrict__ b0,
                         const float* __restrict__ g1, const float* __restrict__ b1,
                         float* __restrict__ abc) {
  int t = threadIdx.x;  // 256
  int p = t >> 7, cix = t & 127;
  const float* bs = bnstat + p * 256;
  float mu = bs[cix] * (1.f / N_NODES);
  float var = bs[128 + cix] * (1.f / N_NODES) - mu * mu;
  float rs = rsqrtf(var + EPS);
  const float* g = p ? g1 : g0;
  const float* b = p ? b1 : b0;
  float av = g[cix] * rs;
  float cv = b[cix] - mu * av;
  abc[t] = av;
  abc[256 + t] = cv;
  abc[512 + t] = (av != 0.f) ? (-cv / av) : 0.f;
}

// Fold BN affine into layer-0 weights.
__global__ __launch_bounds__(256) void cvt_fold(
    const float* __restrict__ Wl0_0, const float* __restrict__ Wr0_0,
    const float* __restrict__ Wl0_1, const float* __restrict__ Wr0_1,
    const float* __restrict__ b0_0, const float* __restrict__ b0_1,
    float* __restrict__ abc, u16* __restrict__ BtAll) {
  int i = blockIdx.x * 256 + threadIdx.x;
  if (i < 65536) {
    int p = i >> 15, q = i & 32767;
    int n = q >> 8, k = q & 255;
    const float* Wl = p ? Wl0_1 : Wl0_0;
    const float* Wr = p ? Wr0_1 : Wr0_0;
    float wv = (k < 128) ? Wl[k * 128 + n] : Wr[(k - 128) * 128 + n];
    float av = abc[p * 128 + (k & 127)];
    BtAll[(size_t)p * 106496 + 32768 + q] = f2bf(wv * av);
  } else if (i < 65536 + 256) {
    int j = i - 65536;
    int p = j >> 7, n = j & 127;
    const float* Wl = p ? Wl0_1 : Wl0_0;
    const float* Wr = p ? Wr0_1 : Wr0_0;
    const float* c = abc + 256 + p * 128;
    float s = (p ? b0_1 : b0_0)[n];
    for (int k = 0; k < 128; k++) s += c[k] * (Wl[k * 128 + n] + Wr[k * 128 + n]);
    abc[768 + j] = s;
  }
}

// pooling counts
__global__ void cnt_count(EdgeArgs ea, int* __restrict__ cnt) {
  int i = blockIdx.x * blockDim.x + threadIdx.x;
  if (i < 2 * N_NODES) {
    int p = i >= N_NODES;
    int k = i - p * N_NODES;
    atomicAdd(&cnt[p * M_ROWS + ea.seg[p][k]], 1);
  }
}

// --------- Phase A: partition edges into NSB super-buckets ------------------
// packed: dst_local(12b) << 17 | src(17b). Tile = 2048 edges, block-local
// counting sort, contiguous chunk copy-out (full-line single-CU writes).
__global__ __launch_bounds__(256) void part_edges(EdgeArgs ea, u32* __restrict__ sbuf,
                                                  int* __restrict__ gcursor) {
  __shared__ u32 lpack[2048];
  __shared__ int hist[NSB], base[NSB], gbase[NSB], lofs[NSB];
  int t = threadIdx.x;
  int e0 = blockIdx.x * 2048;
  if (t < NSB) hist[t] = 0;
  __syncthreads();
  u32 myp[8];
  int myb[8];
#pragma unroll
  for (int q = 0; q < 8; q++) {
    int i = e0 + q * 256 + t;
    int b = -1;
    u32 pk = 0;
    if (i < 2 * E_EDGES) {
      int p = i >= E_EDGES;
      int j = i - p * E_EDGES;
      int d = p * N_NODES + ea.dst[p][j];
      int s = ea.src[p][j];
      b = d >> 12;
      pk = ((u32)(d & 4095) << 17) | (u32)s;
      atomicAdd(&hist[b], 1);
    }
    myb[q] = b;
    myp[q] = pk;
  }
  __syncthreads();
  if (t == 0) {
    int acc = 0;
    for (int b = 0; b < NSB; b++) { base[b] = acc; acc += hist[b]; }
  }
  __syncthreads();
  if (t < NSB) {
    lofs[t] = 0;
    gbase[t] = atomicAdd(&gcursor[t], hist[t]);
  }
  __syncthreads();
#pragma unroll
  for (int q = 0; q < 8; q++) {
    if (myb[q] >= 0) {
      int pos = atomicAdd(&lofs[myb[q]], 1);
      lpack[base[myb[q]] + pos] = myp[q];
    }
  }
  __syncthreads();
  for (int b = 0; b < NSB; b++) {
    int n = hist[b], lb = base[b], gb = gbase[b];
    for (int k = t; k < n; k += 256)
      sbuf[(size_t)b * SB_CAP + gb + k] = lpack[lb + k];
  }
}

// --------- Phase B: per-super-bucket CSR build (one block per bucket) -------
__global__ __launch_bounds__(1024) void build_csr(
    const u32* __restrict__ sbuf, const int* __restrict__ gtot,
    int* __restrict__ offs, float* __restrict__ dinv, u16* __restrict__ colu) {
  __shared__ int ldeg[4096];
  __shared__ int lcur[4096];
  __shared__ int wsum[16];
  __shared__ int sb_tot[NSB];
  int b = blockIdx.x, t = threadIdx.x;
  if (t < NSB) sb_tot[t] = gtot[t];
  for (int k = t; k < 4096; k += 1024) ldeg[k] = 0;
  __syncthreads();
  int edge_base = 0;
  for (int i = 0; i < b; i++) edge_base += sb_tot[i];
  int cnt = sb_tot[b];
  int node0 = b << 12;
  int nend = 2 * N_NODES - node0;
  if (nend > 4096) nend = 4096;
  const u32* me = sbuf + (size_t)b * SB_CAP;
  for (int k = t; k < cnt; k += 1024) atomicAdd(&ldeg[me[k] >> 17], 1);
  __syncthreads();
  // block scan over 4096 (each thread: 4 consecutive)
  int d0 = ldeg[4 * t], d1 = ldeg[4 * t + 1], d2 = ldeg[4 * t + 2], d3 = ldeg[4 * t + 3];
  int ts = d0 + d1 + d2 + d3;
  int lane = t & 63, wid = t >> 6;
  int incl = ts;
#pragma unroll
  for (int off = 1; off < 64; off <<= 1) {
    int u = __shfl_up(incl, off, 64);
    if (lane >= off) incl += u;
  }
  if (lane == 63) wsum[wid] = incl;
  __syncthreads();
  if (t < 64) {
    int v = (t < 16) ? wsum[t] : 0;
    int iv = v;
#pragma unroll
    for (int off = 1; off < 16; off <<= 1) {
      int u = __shfl_up(iv, off, 64);
      if (t >= off) iv += u;
    }
    if (t < 16) wsum[t] = iv - v;
  }
  __syncthreads();
  int ex = wsum[wid] + incl - ts;
  int e1 = ex + d0, e2 = e1 + d1, e3 = e2 + d2;
  int n0 = node0 + 4 * t;
  int lexp[4] = {ex, e1, e2, e3};
  int ldg[4] = {d0, d1, d2, d3};
#pragma unroll
  for (int k = 0; k < 4; k++) {
    if (4 * t + k < nend) {
      offs[n0 + k] = edge_base + lexp[k];
      dinv[n0 + k] = ldg[k] > 0 ? 1.f / (float)ldg[k] : -1.f;
    }
    lcur[4 * t + k] = lexp[k];
  }
  __syncthreads();
  for (int k = t; k < cnt; k += 1024) {
    u32 v = me[k];
    int pos = atomicAdd(&lcur[v >> 17], 1);
    colu[edge_base + pos] = (u16)(v & 0x1FFFFu);
  }
  if (b == 0 && t == 0) offs[2 * N_NODES] = 2 * E_EDGES;
}

// --------- mean-aggregate v2: 1 wave/node, 4 edge-groups x 16 col-lanes ----
// Lane loads uint4 (16B = 8 bf16 cols); main loop = 16 edges/iter -> 4
// independent gathers per lane in flight (whole avg-deg-16 node in ONE
// latency wall). colu reads are group-uniform cache broadcasts. Cross-group
// reduce = 2 shfl_xor per col. dinv<0 marks deg==0 -> nc[panel][col].
__global__ __launch_bounds__(256) void aggregate_bf16(
    const u16* __restrict__ h, const u16* __restrict__ colu,
    const int* __restrict__ offs, const float* __restrict__ dinv,
    const float* __restrict__ nc, u16* __restrict__ agg) {
  int gw = (blockIdx.x * 256 + threadIdx.x) >> 6;
  int lane = threadIdx.x & 63;
  if (gw >= 2 * N_NODES) return;
  int panel = gw >= N_NODES;
  const uint4* hp = (const uint4*)(h + (size_t)panel * N_NODES * 128);
  int grp = lane >> 4, li = lane & 15;
  int s = offs[gw], e = offs[gw + 1];
  float a[8];
#pragma unroll
  for (int k = 0; k < 8; k++) a[k] = 0.f;

  auto acc8 = [&](uint4 v) {
    a[0] += bf2f_lo(v.x); a[1] += bf2f_hi(v.x);
    a[2] += bf2f_lo(v.y); a[3] += bf2f_hi(v.y);
    a[4] += bf2f_lo(v.z); a[5] += bf2f_hi(v.z);
    a[6] += bf2f_lo(v.w); a[7] += bf2f_hi(v.w);
  };

  int j = s;
  for (; j + 16 <= e; j += 16) {
    int c0 = colu[j + grp];
    int c1 = colu[j + 4 + grp];
    int c2 = colu[j + 8 + grp];
    int c3 = colu[j + 12 + grp];
    uint4 v0 = hp[(size_t)c0 * 16 + li];
    uint4 v1 = hp[(size_t)c1 * 16 + li];
    uint4 v2 = hp[(size_t)c2 * 16 + li];
    uint4 v3 = hp[(size_t)c3 * 16 + li];
    acc8(v0); acc8(v1); acc8(v2); acc8(v3);
  }
  for (; j + 4 <= e; j += 4) {
    int c = colu[j + grp];
    uint4 v = hp[(size_t)c * 16 + li];
    acc8(v);
  }
  if (j + grp < e) {
    int c = colu[j + grp];
    uint4 v = hp[(size_t)c * 16 + li];
    acc8(v);
  }

#pragma unroll
  for (int k = 0; k < 8; k++) {
    a[k] += __shfl_xor(a[k], 16);
    a[k] += __shfl_xor(a[k], 32);
  }

  if (grp == 0) {
    float di = dinv[gw];
    float o[8];
    if (di < 0.f) {
      const float* np = nc + panel * 128 + li * 8;
#pragma unroll
      for (int k = 0; k < 8; k++) o[k] = np[k];
    } else {
#pragma unroll
      for (int k = 0; k < 8; k++) o[k] = a[k] * di;
    }
    uint4 ov;
    ov.x = ((u32)f2bf(o[1]) << 16) | (u32)f2bf(o[0]);
    ov.y = ((u32)f2bf(o[3]) << 16) | (u32)f2bf(o[2]);
    ov.z = ((u32)f2bf(o[5]) << 16) | (u32)f2bf(o[4]);
    ov.w = ((u32)f2bf(o[7]) << 16) | (u32)f2bf(o[6]);
    ((uint4*)agg)[(size_t)gw * 16 + li] = ov;
  }
}

__global__ __launch_bounds__(256) void mse_kernel(const float* __restrict__ yb,
                                                  const float* __restrict__ x0,
                                                  const float* __restrict__ x1,
                                                  float* __restrict__ acc) {
  __shared__ float ls[256];
  int pb = blockIdx.y;
  const float* y = yb + (size_t)pb * M_ROWS * OUT_DIM;
  const float* x = pb ? x1 : x0;
  float s = 0.f;
  for (int i = blockIdx.x * 256 + threadIdx.x; i < M_ROWS * OUT_DIM; i += gridDim.x * 256) {
    float d = y[i] - x[i];
    s += d * d;
  }
  ls[threadIdx.x] = s;
  __syncthreads();
  for (int o = 128; o > 0; o >>= 1) {
    if (threadIdx.x < o) ls[threadIdx.x] += ls[threadIdx.x + o];
    __syncthreads();
  }
  if (threadIdx.x == 0) atomicAdd(&acc[pb], ls[0]);
}

__global__ void finalize(const float* __restrict__ acc, float* __restrict__ out) {
  int t = threadIdx.x;
  if (t < 2) out[t] = acc[t] * (1.f / (float)(M_ROWS * OUT_DIM));
}

// ---------------------------------------------------------------------------
extern "C" void kernel_launch(void* const* d_in, const int* in_sizes, int n_in,
                              void* d_out, int out_size, void* d_ws, size_t ws_size,
                              hipStream_t stream) {
  (void)in_sizes; (void)n_in; (void)out_size; (void)ws_size;
  const float* feat[2] = {(const float*)d_in[0], (const float*)d_in[1]};
  const float* xmat[2] = {(const float*)d_in[2], (const float*)d_in[3]};
  const int* esrc[2] = {(const int*)d_in[4], (const int*)d_in[6]};
  const int* edst[2] = {(const int*)d_in[5], (const int*)d_in[7]};
  const int* aseg[2] = {(const int*)d_in[8], (const int*)d_in[9]};

  struct P {
    const float *W_mlp, *b_mlp, *bn_g, *bn_b, *Wl0, *Wr0, *b0, *Wl1, *Wr1, *b1, *Wp, *bp;
  } prm[2];
  for (int p = 0; p < 2; p++) {
    int b = 10 + 12 * p;
    prm[p] = {(const float*)d_in[b + 0], (const float*)d_in[b + 1],
              (const float*)d_in[b + 2], (const float*)d_in[b + 3],
              (const float*)d_in[b + 4], (const float*)d_in[b + 5],
              (const float*)d_in[b + 6], (const float*)d_in[b + 7],
              (const float*)d_in[b + 8], (const float*)d_in[b + 9],
              (const float*)d_in[b + 10], (const float*)d_in[b + 11]};
  }

  char* w = (char*)d_ws;
  auto carve = [&](size_t bytes) -> char* {
    char* r = w;
    w += (bytes + 255) & ~(size_t)255;
    return r;
  };
  // ---- zeroed region (single memset) ----
  char* zbase = w;
  int* gcursor = (int*)carve(NSB * 4);
  int* cnt    = (int*)carve((size_t)2 * M_ROWS * 4);
  float* bnstat = (float*)carve(2 * 256 * 4);
  float* lossacc = (float*)carve(64 * 4);
  float* zerobuf = (float*)carve(256 * 4);
  float* yb   = (float*)carve((size_t)2 * M_ROWS * OUT_DIM * 4);
  size_t zbytes = (size_t)(w - zbase);
  // ---- non-zeroed ----
  u16* hb   = (u16*)carve((size_t)2 * N_NODES * HID * 2);
  u16* aggb = (u16*)carve((size_t)2 * N_NODES * HID * 2);
  u32* sbuf = (u32*)aggb;  // aliased: sbuf dead before first aggregate write
  float* dinv = (float*)carve((size_t)2 * N_NODES * 4);
  float* abc = (float*)carve(1024 * 4);  // a|c|nc|bias0p
  int* offs = (int*)carve((size_t)(2 * N_NODES + 1) * 4);
  u16* colu = (u16*)carve((size_t)2 * E_EDGES * 2);
  u16* BtAll = (u16*)carve((size_t)2 * 106496 * 2);

  const int TWO_N = 2 * N_NODES;

  EdgeArgs ea;
  for (int p = 0; p < 2; p++) { ea.src[p] = esrc[p]; ea.dst[p] = edst[p]; ea.seg[p] = aseg[p]; }

  CvtArgs ca;
  for (int p = 0; p < 2; p++) {
    ca.W[p * 6 + 0] = prm[p].W_mlp; ca.W[p * 6 + 1] = prm[p].Wl0;
    ca.W[p * 6 + 2] = prm[p].Wr0;   ca.W[p * 6 + 3] = prm[p].Wl1;
    ca.W[p * 6 + 4] = prm[p].Wr1;   ca.W[p * 6 + 5] = prm[p].Wp;
  }
  ca.Bt = BtAll;

  auto mkga = [&](int mode, int layer) {
    GArgs g{};
    for (int p = 0; p < 2; p++) {
      u16* hp = hb + (size_t)p * N_NODES * HID;
      const u16* btp = BtAll + (size_t)p * 106496;
      g.Cb[p] = hp;
      g.bnsum[p] = bnstat + p * 256;
      g.bnss[p] = bnstat + p * 256 + 128;
      g.seg[p] = aseg[p];
      g.cnt[p] = cnt + p * M_ROWS;
      g.y[p] = yb + (size_t)p * M_ROWS * OUT_DIM;
      if (mode == 0) {
        g.A1[p] = feat[p];
        g.Bt[p] = btp;
        g.bias[p] = prm[p].b_mlp;
      } else if (mode == 1) {
        g.A1[p] = hp;
        g.A2[p] = aggb + (size_t)p * N_NODES * HID;
        g.Bt[p] = btp + (layer ? 65536 : 32768);
        g.bias[p] = layer ? prm[p].b1 : (const float*)(abc + 768 + p * 128);
      } else {
        g.A1[p] = hp;
        g.Bt[p] = btp + 98304;
        g.bias[p] = prm[p].bp;
      }
    }
    return g;
  };

  const int GX = (N_NODES + 127) / 128;  // 391 blocks of 128 rows (8 waves x 16)

  hipMemsetAsync(zbase, 0, zbytes, stream);
  cvt_weightsA<<<(2 * 106496 + 255) / 256, 256, 0, stream>>>(ca);
  // edge partition + CSR build (runs while encode GEMM params prepared)
  part_edges<<<(2 * E_EDGES + 2047) / 2048, 256, 0, stream>>>(ea, sbuf, gcursor);
  build_csr<<<NSB, 1024, 0, stream>>>(sbuf, gcursor, offs, dinv, colu);
  cnt_count<<<(TWO_N + 255) / 256, 256, 0, stream>>>(ea, cnt);
  // encode (both panels) + BN stats; h stays PRE-BN (affine folded downstream)
  gemm_stream<128, 0, IN_DIM><<<dim3(GX, 2), 512, 0, stream>>>(mkga(0, 0), N_NODES);
  bn_final<<<1, 256, 0, stream>>>(bnstat, prm[0].bn_g, prm[0].bn_b,
                                  prm[1].bn_g, prm[1].bn_b, abc);
  cvt_fold<<<(65536 + 256 + 255) / 256, 256, 0, stream>>>(
      prm[0].Wl0, prm[0].Wr0, prm[1].Wl0, prm[1].Wr0, prm[0].b0, prm[1].b0,
      abc, BtAll);
  // SAGE layer 0 (raw h + BN-folded weights; deg==0 rows patched with nc)
  aggregate_bf16<<<(TWO_N * 64 + 255) / 256, 256, 0, stream>>>(
      hb, colu, offs, dinv, abc + 512, aggb);
  gemm_stream<128, 1, 2 * HID><<<dim3(GX, 2), 512, 0, stream>>>(mkga(1, 0), N_NODES);
  // SAGE layer 1 (in-place h; deg==0 rows -> 0)
  aggregate_bf16<<<(TWO_N * 64 + 255) / 256, 256, 0, stream>>>(
      hb, colu, offs, dinv, zerobuf, aggb);
  gemm_stream<128, 1, 2 * HID><<<dim3(GX, 2), 512, 0, stream>>>(mkga(1, 1), N_NODES);
  // projection + mean-pool
  gemm_stream<64, 2, HID><<<dim3(GX, 2), 512, 0, stream>>>(mkga(2, 0), N_NODES);
  mse_kernel<<<dim3(128, 2), 256, 0, stream>>>(yb, xmat[0], xmat[1], lossacc);
  finalize<<<1, 64, 0, stream>>>(lossacc, (float*)d_out);
}

// Round 4
// 304.132 us; speedup vs baseline: 1.3743x; 1.1129x over previous
//
#include <hip/hip_runtime.h>

#define N_NODES 50000
#define E_EDGES 800000
#define M_ROWS  12500
#define IN_DIM  256
#define HID     128
#define OUT_DIM 64
#define EPS     1e-5f
#define SLOPE   0.1f
#define SB_BITS 9
#define SB_SIZE 512
#define NSB     196         // ceil(2N / 512) super-buckets
#define SB_CAP  (12 * 1024) // mean 8192, sigma~90 -> 45 sigma; fixed inputs safe

typedef unsigned short u16;
typedef unsigned int u32;
typedef __attribute__((ext_vector_type(8))) short short8;
typedef __attribute__((ext_vector_type(4))) float f32x4;

__device__ __forceinline__ float leaky_f(float x) { return x >= 0.f ? x : SLOPE * x; }

__device__ __forceinline__ u16 f2bf(float f) {
  u32 x = __float_as_uint(f);
  return (u16)((x + 0x7fffu + ((x >> 16) & 1u)) >> 16);
}
__device__ __forceinline__ float bf2f(u16 u) { return __uint_as_float((u32)u << 16); }
__device__ __forceinline__ float bf2f_lo(u32 v) { return __uint_as_float(v << 16); }
__device__ __forceinline__ float bf2f_hi(u32 v) { return __uint_as_float(v & 0xffff0000u); }

struct GArgs {
  const void* A1[2];
  const void* A2[2];
  const u16* Bt[2];
  const float* bias[2];
  u16* Cb[2];
  float* bnsum[2];
  float* bnss[2];
  const int* seg[2];
  const int* cnt[2];
  float* y[2];
};

struct EdgeArgs {
  const int* src[2];
  const int* dst[2];
  const int* seg[2];
};

struct CvtArgs {
  const float* W[12];
  u16* Bt;
};

// ---------------------------------------------------------------------------
// One-latency-wall streaming MFMA GEMM. 512 threads = 8 waves; wave owns a
// 16-row x BN strip. Prologue: B-staging loads -> all A loads (full K) ->
// ds_write B -> ONE __syncthreads. Steady state: pure ds_read+MFMA.
// MODE 0 ENCODE: A1 = f32; C = bf16 leaky; BN col stats via LDS block-reduce.
// MODE 1 LAYER : A1,A2 = bf16 (K split 128+128); C = bf16 leaky (in-place
//                safe: waves only write rows they own).
// MODE 2 POOL  : A1 = bf16; no act; atomicAdd (v*w) into y[seg[row]][col].
// ---------------------------------------------------------------------------
template <int BN, int MODE, int KTOT>
__global__ __launch_bounds__(512, 2) void gemm_stream(GArgs ga, int nrows) {
  constexpr int NI = BN / 16;
  constexpr int KT = KTOT / 32;
  constexpr int LDK = KTOT + 8;                 // pad 8 u16 = 16B
  constexpr int BEL = BN * KTOT;                // B elements
  constexpr int SIT = BEL / (512 * 8);          // staging iters
  constexpr int KSH = (KTOT == 256) ? 8 : 7;
  __shared__ u16 Bs[BN * LDK];
  __shared__ float redS[(MODE == 0) ? 128 : 1];
  __shared__ float redQ[(MODE == 0) ? 128 : 1];

  const int pb = blockIdx.y;
  const int t = threadIdx.x;
  const int w = t >> 6, lane = t & 63;
  const int laneM = lane & 15, kg = lane >> 4;
  const int r0 = blockIdx.x * 128 + w * 16;

  const u16* Bt = ga.Bt[pb];
  const float* bias = ga.bias[pb];

  int ra = r0 + laneM;
  if (ra >= nrows) ra = nrows - 1;

  // ---- (1) B-staging loads first (oldest in vmcnt queue) ----
  short8 sreg[SIT];
#pragma unroll
  for (int si = 0; si < SIT; si++)
    sreg[si] = *(const short8*)(Bt + si * 4096 + t * 8);

  // ---- (2) full-K A prefetch: independent HBM loads, one latency wall ----
  float4 pf[(MODE == 0) ? 2 * KT : 1];
  short8 af[(MODE == 0) ? 1 : KT];
  if constexpr (MODE == 0) {
    const float* A = (const float*)ga.A1[pb] + (size_t)ra * KTOT + kg * 8;
#pragma unroll
    for (int kt = 0; kt < KT; kt++) {
      pf[2 * kt] = *(const float4*)(A + kt * 32);
      pf[2 * kt + 1] = *(const float4*)(A + kt * 32 + 4);
    }
  } else if constexpr (MODE == 1) {
    const u16* A1 = (const u16*)ga.A1[pb] + (size_t)ra * HID + kg * 8;
    const u16* A2 = (const u16*)ga.A2[pb] + (size_t)ra * HID + kg * 8;
#pragma unroll
    for (int kt = 0; kt < KT / 2; kt++) af[kt] = *(const short8*)(A1 + kt * 32);
#pragma unroll
    for (int kt = 0; kt < KT / 2; kt++)
      af[KT / 2 + kt] = *(const short8*)(A2 + kt * 32);
  } else {
    const u16* A1 = (const u16*)ga.A1[pb] + (size_t)ra * HID + kg * 8;
#pragma unroll
    for (int kt = 0; kt < KT; kt++) af[kt] = *(const short8*)(A1 + kt * 32);
  }

  // ---- (3) write staged B to padded LDS ----
  if constexpr (MODE == 0) {
    if (t < 128) { redS[t] = 0.f; redQ[t] = 0.f; }
  }
#pragma unroll
  for (int si = 0; si < SIT; si++) {
    int i = si * 4096 + t * 8;
    int n = i >> KSH;
    int k = i & (KTOT - 1);
    *(short8*)&Bs[n * LDK + k] = sreg[si];
  }
  __syncthreads();

  // ---- steady state: pure LDS + MFMA ----
  f32x4 acc[NI];
#pragma unroll
  for (int ni = 0; ni < NI; ni++) acc[ni] = (f32x4){0.f, 0.f, 0.f, 0.f};

#pragma unroll
  for (int kt = 0; kt < KT; kt++) {
    const int k0 = kt * 32 + kg * 8;
    short8 a;
    if constexpr (MODE == 0) {
      float4 v0 = pf[2 * kt], v1 = pf[2 * kt + 1];
      a[0] = (short)f2bf(v0.x); a[1] = (short)f2bf(v0.y);
      a[2] = (short)f2bf(v0.z); a[3] = (short)f2bf(v0.w);
      a[4] = (short)f2bf(v1.x); a[5] = (short)f2bf(v1.y);
      a[6] = (short)f2bf(v1.z); a[7] = (short)f2bf(v1.w);
    } else {
      a = af[kt];
    }
#pragma unroll
    for (int ni = 0; ni < NI; ni++) {
      short8 b = *(const short8*)&Bs[(ni * 16 + laneM) * LDK + k0];
      acc[ni] = __builtin_amdgcn_mfma_f32_16x16x32_bf16(a, b, acc[ni], 0, 0, 0);
    }
  }

  // ---- epilogue ----
  float bcol[NI];
#pragma unroll
  for (int ni = 0; ni < NI; ni++) bcol[ni] = bias[ni * 16 + laneM];

  float ssum[NI], ssq[NI];
#pragma unroll
  for (int ni = 0; ni < NI; ni++) { ssum[ni] = 0.f; ssq[ni] = 0.f; }

#pragma unroll
  for (int r = 0; r < 4; r++) {
    int gr = r0 + kg * 4 + r;
    if (gr >= nrows) continue;
    float pw = 0.f;
    int sI = 0;
    if constexpr (MODE == 2) {
      sI = ga.seg[pb][gr];
      int cv = ga.cnt[pb][sI];
      pw = 1.f / (float)(cv > 1 ? cv : 1);
    }
#pragma unroll
    for (int ni = 0; ni < NI; ni++) {
      int col = ni * 16 + laneM;
      float v = acc[ni][r] + bcol[ni];
      if constexpr (MODE == 0) {
        v = leaky_f(v);
        ga.Cb[pb][(size_t)gr * BN + col] = f2bf(v);
        ssum[ni] += v;
        ssq[ni] += v * v;
      } else if constexpr (MODE == 1) {
        v = leaky_f(v);
        ga.Cb[pb][(size_t)gr * BN + col] = f2bf(v);
      } else {
        atomicAdd(&ga.y[pb][(size_t)sI * OUT_DIM + col], v * pw);
      }
    }
  }

  if constexpr (MODE == 0) {
#pragma unroll
    for (int ni = 0; ni < NI; ni++) {
      float a = ssum[ni], b = ssq[ni];
      a += __shfl_xor(a, 16); a += __shfl_xor(a, 32);
      b += __shfl_xor(b, 16); b += __shfl_xor(b, 32);
      if (kg == 0) {
        atomicAdd(&redS[ni * 16 + laneM], a);
        atomicAdd(&redQ[ni * 16 + laneM], b);
      }
    }
    __syncthreads();
    if (t < 128) {
      atomicAdd(&ga.bnsum[pb][t], redS[t]);
      atomicAdd(&ga.bnss[pb][t], redQ[t]);
    }
  }
}

// Weights -> bf16 transposed Bt[n][k]; SKIPS Bt0 (folded later with BN affine).
__global__ __launch_bounds__(256) void cvt_weightsA(CvtArgs a) {
  int i = blockIdx.x * 256 + threadIdx.x;
  if (i >= 2 * 106496) return;
  int p = i >= 106496;
  int j = i - p * 106496;
  const float* const* W = a.W + p * 6;
  u16* out = a.Bt + (size_t)p * 106496;
  if (j < 32768) {
    int n = j >> 8, k = j & 255;
    out[j] = f2bf(W[0][k * 128 + n]);
  } else if (j < 65536) {
    return;
  } else if (j < 98304) {
    int q = j - 65536, n = q >> 8, k = q & 255;
    out[j] = f2bf(k < 128 ? W[3][k * 128 + n] : W[4][(k - 128) * 128 + n]);
  } else {
    int q = j - 98304, n = q >> 7, k = q & 127;
    out[j] = f2bf(W[5][k * 64 + n]);
  }
}

// abc layout: a[256] | c[256] | nc[256] | bias0p[256]
__global__ void bn_final(const float* __restrict__ bnstat,
                         const float* __restrict__ g0, const float* __restrict__ b0,
                         const float* __restrict__ g1, const float* __restrict__ b1,
                         float* __restrict__ abc) {
  int t = threadIdx.x;  // 256
  int p = t >> 7, cix = t & 127;
  const float* bs = bnstat + p * 256;
  float mu = bs[cix] * (1.f / N_NODES);
  float var = bs[128 + cix] * (1.f / N_NODES) - mu * mu;
  float rs = rsqrtf(var + EPS);
  const float* g = p ? g1 : g0;
  const float* b = p ? b1 : b0;
  float av = g[cix] * rs;
  float cv = b[cix] - mu * av;
  abc[t] = av;
  abc[256 + t] = cv;
  abc[512 + t] = (av != 0.f) ? (-cv / av) : 0.f;
}

// Fold BN affine into layer-0 weights.
__global__ __launch_bounds__(256) void cvt_fold(
    const float* __restrict__ Wl0_0, const float* __restrict__ Wr0_0,
    const float* __restrict__ Wl0_1, const float* __restrict__ Wr0_1,
    const float* __restrict__ b0_0, const float* __restrict__ b0_1,
    float* __restrict__ abc, u16* __restrict__ BtAll) {
  int i = blockIdx.x * 256 + threadIdx.x;
  if (i < 65536) {
    int p = i >> 15, q = i & 32767;
    int n = q >> 8, k = q & 255;
    const float* Wl = p ? Wl0_1 : Wl0_0;
    const float* Wr = p ? Wr0_1 : Wr0_0;
    float wv = (k < 128) ? Wl[k * 128 + n] : Wr[(k - 128) * 128 + n];
    float av = abc[p * 128 + (k & 127)];
    BtAll[(size_t)p * 106496 + 32768 + q] = f2bf(wv * av);
  } else if (i < 65536 + 256) {
    int j = i - 65536;
    int p = j >> 7, n = j & 127;
    const float* Wl = p ? Wl0_1 : Wl0_0;
    const float* Wr = p ? Wr0_1 : Wr0_0;
    const float* c = abc + 256 + p * 128;
    float s = (p ? b0_1 : b0_0)[n];
    for (int k = 0; k < 128; k++) s += c[k] * (Wl[k * 128 + n] + Wr[k * 128 + n]);
    abc[768 + j] = s;
  }
}

// pooling counts
__global__ void cnt_count(EdgeArgs ea, int* __restrict__ cnt) {
  int i = blockIdx.x * blockDim.x + threadIdx.x;
  if (i < 2 * N_NODES) {
    int p = i >= N_NODES;
    int k = i - p * N_NODES;
    atomicAdd(&cnt[p * M_ROWS + ea.seg[p][k]], 1);
  }
}

// --------- Phase A: partition edges into NSB super-buckets ------------------
// packed: dst_local(9b) << 17 | src(16b). Tile = 2048 edges, block-local
// counting sort, wave-per-bucket chunk copy-out.
__global__ __launch_bounds__(256) void part_edges(EdgeArgs ea, u32* __restrict__ sbuf,
                                                  int* __restrict__ gcursor) {
  __shared__ u32 lpack[2048];
  __shared__ int hist[NSB], base[NSB], gbase[NSB], lofs[NSB];
  int t = threadIdx.x;
  int e0 = blockIdx.x * 2048;
  for (int i = t; i < NSB; i += 256) hist[i] = 0;
  __syncthreads();
  u32 myp[8];
  int myb[8];
#pragma unroll
  for (int q = 0; q < 8; q++) {
    int i = e0 + q * 256 + t;
    int b = -1;
    u32 pk = 0;
    if (i < 2 * E_EDGES) {
      int p = i >= E_EDGES;
      int j = i - p * E_EDGES;
      int d = p * N_NODES + ea.dst[p][j];
      int s = ea.src[p][j];
      b = d >> SB_BITS;
      pk = ((u32)(d & (SB_SIZE - 1)) << 17) | (u32)s;
      atomicAdd(&hist[b], 1);
    }
    myb[q] = b;
    myp[q] = pk;
  }
  __syncthreads();
  if (t == 0) {
    int acc = 0;
    for (int b = 0; b < NSB; b++) { base[b] = acc; acc += hist[b]; }
  }
  __syncthreads();
  for (int i = t; i < NSB; i += 256) {
    lofs[i] = 0;
    gbase[i] = atomicAdd(&gcursor[i], hist[i]);
  }
  __syncthreads();
#pragma unroll
  for (int q = 0; q < 8; q++) {
    if (myb[q] >= 0) {
      int pos = atomicAdd(&lofs[myb[q]], 1);
      lpack[base[myb[q]] + pos] = myp[q];
    }
  }
  __syncthreads();
  int wid = t >> 6, lane = t & 63;
  for (int b = wid; b < NSB; b += 4) {
    int n = hist[b], lb = base[b], gb = gbase[b];
    for (int k = lane; k < n; k += 64)
      sbuf[(size_t)b * SB_CAP + gb + k] = lpack[lb + k];
  }
}

// --------- Phase B: per-super-bucket CSR build (one block per bucket) -------
// 196 blocks x 512 threads; 512-node buckets -> ~8K edges/block.
__global__ __launch_bounds__(512) void build_csr(
    const u32* __restrict__ sbuf, const int* __restrict__ gtot,
    int* __restrict__ offs, float* __restrict__ dinv, u16* __restrict__ colu) {
  __shared__ int ldeg[SB_SIZE];
  __shared__ int lcur[SB_SIZE];
  __shared__ int wsum[8];
  __shared__ int sbase_s;
  int b = blockIdx.x, t = threadIdx.x;
  int lane = t & 63, wid = t >> 6;
  ldeg[t] = 0;
  if (t < 64) {
    // edge_base = sum of gtot[0..b) via 64-lane masked sum + butterfly
    int s = 0;
    for (int i = lane; i < b; i += 64) s += gtot[i];
#pragma unroll
    for (int off = 1; off < 64; off <<= 1) s += __shfl_xor(s, off, 64);
    if (lane == 0) sbase_s = s;
  }
  __syncthreads();
  const int cnt = gtot[b];
  const int edge_base = sbase_s;
  const int node0 = b << SB_BITS;
  int nend = 2 * N_NODES - node0;
  if (nend > SB_SIZE) nend = SB_SIZE;
  const u32* me = sbuf + (size_t)b * SB_CAP;
  for (int k = t; k < cnt; k += 512) atomicAdd(&ldeg[me[k] >> 17], 1);
  __syncthreads();
  // block scan over 512 (one node per thread)
  int d = ldeg[t];
  int incl = d;
#pragma unroll
  for (int off = 1; off < 64; off <<= 1) {
    int u = __shfl_up(incl, off, 64);
    if (lane >= off) incl += u;
  }
  if (lane == 63) wsum[wid] = incl;
  __syncthreads();
  if (t == 0) {
    int acc = 0;
#pragma unroll
    for (int i = 0; i < 8; i++) { int v = wsum[i]; wsum[i] = acc; acc += v; }
  }
  __syncthreads();
  int ex = wsum[wid] + incl - d;
  if (t < nend) {
    offs[node0 + t] = edge_base + ex;
    dinv[node0 + t] = d > 0 ? 1.f / (float)d : -1.f;
  }
  lcur[t] = ex;
  __syncthreads();
  for (int k = t; k < cnt; k += 512) {
    u32 v = me[k];
    int pos = atomicAdd(&lcur[v >> 17], 1);
    colu[edge_base + pos] = (u16)(v & 0xFFFFu);
  }
  if (b == 0 && t == 0) offs[2 * N_NODES] = 2 * E_EDGES;
}

// --------- mean-aggregate v2: 1 wave/node, 4 edge-groups x 16 col-lanes ----
// Lane loads uint4 (16B = 8 bf16 cols); main loop = 16 edges/iter -> 4
// independent gathers per lane in flight. dinv<0 marks deg==0 -> nc[col].
__global__ __launch_bounds__(256) void aggregate_bf16(
    const u16* __restrict__ h, const u16* __restrict__ colu,
    const int* __restrict__ offs, const float* __restrict__ dinv,
    const float* __restrict__ nc, u16* __restrict__ agg) {
  int gw = (blockIdx.x * 256 + threadIdx.x) >> 6;
  int lane = threadIdx.x & 63;
  if (gw >= 2 * N_NODES) return;
  int panel = gw >= N_NODES;
  const uint4* hp = (const uint4*)(h + (size_t)panel * N_NODES * 128);
  int grp = lane >> 4, li = lane & 15;
  int s = offs[gw], e = offs[gw + 1];
  float a[8];
#pragma unroll
  for (int k = 0; k < 8; k++) a[k] = 0.f;

  auto acc8 = [&](uint4 v) {
    a[0] += bf2f_lo(v.x); a[1] += bf2f_hi(v.x);
    a[2] += bf2f_lo(v.y); a[3] += bf2f_hi(v.y);
    a[4] += bf2f_lo(v.z); a[5] += bf2f_hi(v.z);
    a[6] += bf2f_lo(v.w); a[7] += bf2f_hi(v.w);
  };

  int j = s;
  for (; j + 16 <= e; j += 16) {
    int c0 = colu[j + grp];
    int c1 = colu[j + 4 + grp];
    int c2 = colu[j + 8 + grp];
    int c3 = colu[j + 12 + grp];
    uint4 v0 = hp[(size_t)c0 * 16 + li];
    uint4 v1 = hp[(size_t)c1 * 16 + li];
    uint4 v2 = hp[(size_t)c2 * 16 + li];
    uint4 v3 = hp[(size_t)c3 * 16 + li];
    acc8(v0); acc8(v1); acc8(v2); acc8(v3);
  }
  for (; j + 4 <= e; j += 4) {
    int c = colu[j + grp];
    uint4 v = hp[(size_t)c * 16 + li];
    acc8(v);
  }
  if (j + grp < e) {
    int c = colu[j + grp];
    uint4 v = hp[(size_t)c * 16 + li];
    acc8(v);
  }

#pragma unroll
  for (int k = 0; k < 8; k++) {
    a[k] += __shfl_xor(a[k], 16);
    a[k] += __shfl_xor(a[k], 32);
  }

  if (grp == 0) {
    float di = dinv[gw];
    float o[8];
    if (di < 0.f) {
      const float* np = nc + panel * 128 + li * 8;
#pragma unroll
      for (int k = 0; k < 8; k++) o[k] = np[k];
    } else {
#pragma unroll
      for (int k = 0; k < 8; k++) o[k] = a[k] * di;
    }
    uint4 ov;
    ov.x = ((u32)f2bf(o[1]) << 16) | (u32)f2bf(o[0]);
    ov.y = ((u32)f2bf(o[3]) << 16) | (u32)f2bf(o[2]);
    ov.z = ((u32)f2bf(o[5]) << 16) | (u32)f2bf(o[4]);
    ov.w = ((u32)f2bf(o[7]) << 16) | (u32)f2bf(o[6]);
    ((uint4*)agg)[(size_t)gw * 16 + li] = ov;
  }
}

__global__ __launch_bounds__(256) void mse_kernel(const float* __restrict__ yb,
                                                  const float* __restrict__ x0,
                                                  const float* __restrict__ x1,
                                                  float* __restrict__ acc) {
  __shared__ float ls[256];
  int pb = blockIdx.y;
  const float* y = yb + (size_t)pb * M_ROWS * OUT_DIM;
  const float* x = pb ? x1 : x0;
  float s = 0.f;
  for (int i = blockIdx.x * 256 + threadIdx.x; i < M_ROWS * OUT_DIM; i += gridDim.x * 256) {
    float d = y[i] - x[i];
    s += d * d;
  }
  ls[threadIdx.x] = s;
  __syncthreads();
  for (int o = 128; o > 0; o >>= 1) {
    if (threadIdx.x < o) ls[threadIdx.x] += ls[threadIdx.x + o];
    __syncthreads();
  }
  if (threadIdx.x == 0) atomicAdd(&acc[pb], ls[0]);
}

__global__ void finalize(const float* __restrict__ acc, float* __restrict__ out) {
  int t = threadIdx.x;
  if (t < 2) out[t] = acc[t] * (1.f / (float)(M_ROWS * OUT_DIM));
}

// ---------------------------------------------------------------------------
extern "C" void kernel_launch(void* const* d_in, const int* in_sizes, int n_in,
                              void* d_out, int out_size, void* d_ws, size_t ws_size,
                              hipStream_t stream) {
  (void)in_sizes; (void)n_in; (void)out_size; (void)ws_size;
  const float* feat[2] = {(const float*)d_in[0], (const float*)d_in[1]};
  const float* xmat[2] = {(const float*)d_in[2], (const float*)d_in[3]};
  const int* esrc[2] = {(const int*)d_in[4], (const int*)d_in[6]};
  const int* edst[2] = {(const int*)d_in[5], (const int*)d_in[7]};
  const int* aseg[2] = {(const int*)d_in[8], (const int*)d_in[9]};

  struct P {
    const float *W_mlp, *b_mlp, *bn_g, *bn_b, *Wl0, *Wr0, *b0, *Wl1, *Wr1, *b1, *Wp, *bp;
  } prm[2];
  for (int p = 0; p < 2; p++) {
    int b = 10 + 12 * p;
    prm[p] = {(const float*)d_in[b + 0], (const float*)d_in[b + 1],
              (const float*)d_in[b + 2], (const float*)d_in[b + 3],
              (const float*)d_in[b + 4], (const float*)d_in[b + 5],
              (const float*)d_in[b + 6], (const float*)d_in[b + 7],
              (const float*)d_in[b + 8], (const float*)d_in[b + 9],
              (const float*)d_in[b + 10], (const float*)d_in[b + 11]};
  }

  char* w = (char*)d_ws;
  auto carve = [&](size_t bytes) -> char* {
    char* r = w;
    w += (bytes + 255) & ~(size_t)255;
    return r;
  };
  // ---- zeroed region (single memset) ----
  char* zbase = w;
  int* gcursor = (int*)carve(NSB * 4);
  int* cnt    = (int*)carve((size_t)2 * M_ROWS * 4);
  float* bnstat = (float*)carve(2 * 256 * 4);
  float* lossacc = (float*)carve(64 * 4);
  float* zerobuf = (float*)carve(256 * 4);
  float* yb   = (float*)carve((size_t)2 * M_ROWS * OUT_DIM * 4);
  size_t zbytes = (size_t)(w - zbase);
  // ---- non-zeroed ----
  u16* hb   = (u16*)carve((size_t)2 * N_NODES * HID * 2);
  u16* aggb = (u16*)carve((size_t)2 * N_NODES * HID * 2);
  u32* sbuf = (u32*)aggb;  // aliased: sbuf (9.6MB) dead before first aggregate write
  float* dinv = (float*)carve((size_t)2 * N_NODES * 4);
  float* abc = (float*)carve(1024 * 4);  // a|c|nc|bias0p
  int* offs = (int*)carve((size_t)(2 * N_NODES + 1) * 4);
  u16* colu = (u16*)carve((size_t)2 * E_EDGES * 2);
  u16* BtAll = (u16*)carve((size_t)2 * 106496 * 2);

  const int TWO_N = 2 * N_NODES;

  EdgeArgs ea;
  for (int p = 0; p < 2; p++) { ea.src[p] = esrc[p]; ea.dst[p] = edst[p]; ea.seg[p] = aseg[p]; }

  CvtArgs ca;
  for (int p = 0; p < 2; p++) {
    ca.W[p * 6 + 0] = prm[p].W_mlp; ca.W[p * 6 + 1] = prm[p].Wl0;
    ca.W[p * 6 + 2] = prm[p].Wr0;   ca.W[p * 6 + 3] = prm[p].Wl1;
    ca.W[p * 6 + 4] = prm[p].Wr1;   ca.W[p * 6 + 5] = prm[p].Wp;
  }
  ca.Bt = BtAll;

  auto mkga = [&](int mode, int layer) {
    GArgs g{};
    for (int p = 0; p < 2; p++) {
      u16* hp = hb + (size_t)p * N_NODES * HID;
      const u16* btp = BtAll + (size_t)p * 106496;
      g.Cb[p] = hp;
      g.bnsum[p] = bnstat + p * 256;
      g.bnss[p] = bnstat + p * 256 + 128;
      g.seg[p] = aseg[p];
      g.cnt[p] = cnt + p * M_ROWS;
      g.y[p] = yb + (size_t)p * M_ROWS * OUT_DIM;
      if (mode == 0) {
        g.A1[p] = feat[p];
        g.Bt[p] = btp;
        g.bias[p] = prm[p].b_mlp;
      } else if (mode == 1) {
        g.A1[p] = hp;
        g.A2[p] = aggb + (size_t)p * N_NODES * HID;
        g.Bt[p] = btp + (layer ? 65536 : 32768);
        g.bias[p] = layer ? prm[p].b1 : (const float*)(abc + 768 + p * 128);
      } else {
        g.A1[p] = hp;
        g.Bt[p] = btp + 98304;
        g.bias[p] = prm[p].bp;
      }
    }
    return g;
  };

  const int GX = (N_NODES + 127) / 128;  // 391 blocks of 128 rows (8 waves x 16)

  hipMemsetAsync(zbase, 0, zbytes, stream);
  cvt_weightsA<<<(2 * 106496 + 255) / 256, 256, 0, stream>>>(ca);
  // edge partition + CSR build
  part_edges<<<(2 * E_EDGES + 2047) / 2048, 256, 0, stream>>>(ea, sbuf, gcursor);
  build_csr<<<NSB, 512, 0, stream>>>(sbuf, gcursor, offs, dinv, colu);
  cnt_count<<<(TWO_N + 255) / 256, 256, 0, stream>>>(ea, cnt);
  // encode (both panels) + BN stats; h stays PRE-BN (affine folded downstream)
  gemm_stream<128, 0, IN_DIM><<<dim3(GX, 2), 512, 0, stream>>>(mkga(0, 0), N_NODES);
  bn_final<<<1, 256, 0, stream>>>(bnstat, prm[0].bn_g, prm[0].bn_b,
                                  prm[1].bn_g, prm[1].bn_b, abc);
  cvt_fold<<<(65536 + 256 + 255) / 256, 256, 0, stream>>>(
      prm[0].Wl0, prm[0].Wr0, prm[1].Wl0, prm[1].Wr0, prm[0].b0, prm[1].b0,
      abc, BtAll);
  // SAGE layer 0 (raw h + BN-folded weights; deg==0 rows patched with nc)
  aggregate_bf16<<<(TWO_N * 64 + 255) / 256, 256, 0, stream>>>(
      hb, colu, offs, dinv, abc + 512, aggb);
  gemm_stream<128, 1, 2 * HID><<<dim3(GX, 2), 512, 0, stream>>>(mkga(1, 0), N_NODES);
  // SAGE layer 1 (in-place h; deg==0 rows -> 0)
  aggregate_bf16<<<(TWO_N * 64 + 255) / 256, 256, 0, stream>>>(
      hb, colu, offs, dinv, zerobuf, aggb);
  gemm_stream<128, 1, 2 * HID><<<dim3(GX, 2), 512, 0, stream>>>(mkga(1, 1), N_NODES);
  // projection + mean-pool
  gemm_stream<64, 2, HID><<<dim3(GX, 2), 512, 0, stream>>>(mkga(2, 0), N_NODES);
  mse_kernel<<<dim3(128, 2), 256, 0, stream>>>(yb, xmat[0], xmat[1], lossacc);
  finalize<<<1, 64, 0, stream>>>(lossacc, (float*)d_out);
}

// Round 5
// 303.499 us; speedup vs baseline: 1.3772x; 1.0021x over previous
//
#include <hip/hip_runtime.h>

#define N_NODES 50000
#define E_EDGES 800000
#define M_ROWS  12500
#define IN_DIM  256
#define HID     128
#define OUT_DIM 64
#define EPS     1e-5f
#define SLOPE   0.1f
#define SB_BITS 9
#define SB_SIZE 512
#define NSB     196         // ceil(2N / 512) super-buckets
#define SB_CAP  (12 * 1024) // mean 8192, sigma~90 -> 45 sigma; fixed inputs safe

typedef unsigned short u16;
typedef unsigned int u32;
typedef __attribute__((ext_vector_type(8))) short short8;
typedef __attribute__((ext_vector_type(4))) float f32x4;

__device__ __forceinline__ float leaky_f(float x) { return x >= 0.f ? x : SLOPE * x; }

__device__ __forceinline__ u16 f2bf(float f) {
  u32 x = __float_as_uint(f);
  return (u16)((x + 0x7fffu + ((x >> 16) & 1u)) >> 16);
}
__device__ __forceinline__ float bf2f(u16 u) { return __uint_as_float((u32)u << 16); }
__device__ __forceinline__ float bf2f_lo(u32 v) { return __uint_as_float(v << 16); }
__device__ __forceinline__ float bf2f_hi(u32 v) { return __uint_as_float(v & 0xffff0000u); }

struct GArgs {
  const void* A1[2];
  const void* A2[2];
  const u16* Bt[2];
  const float* bias[2];
  u16* Cb[2];
  float* bnsum[2];
  float* bnss[2];
  const int* seg[2];
  const int* cnt[2];
  float* y[2];
};

struct EdgeArgs {
  const int* src[2];
  const int* dst[2];
  const int* seg[2];
};

struct CvtArgs {
  const float* W[12];
  u16* Bt;
};

// ---------------------------------------------------------------------------
// One-latency-wall streaming MFMA GEMM. 512 threads = 8 waves; wave owns a
// 16-row x BN strip. Prologue: issue B-staging + full-K A loads back-to-back,
// then sched_barrier(0) PINS the issue cluster (R4 post-mortem: without the
// pin, hipcc's min-pressure scheduler sank every load to its use -> serial
// vmcnt(0) chain, VGPR_Count=56, 60us. The pin forces regalloc to keep the
// prefetch live -> ONE parallel latency wall). __launch_bounds__(512,4) caps
// VGPR at 128 -> 2 blocks/CU (matches 67.6KB LDS) so one block's fetch
// overlaps the other's compute.
// MODE 0 ENCODE: A1 = f32, K in 2 halves (pf[8] reused, WAR-ordered) to stay
//                under the 128-reg cap; C = bf16 leaky; BN stats LDS-reduced.
// MODE 1 LAYER : A1,A2 = bf16 (K split 128+128); C = bf16 leaky (in-place
//                safe: waves only write rows they own).
// MODE 2 POOL  : A1 = bf16; no act; atomicAdd (v*w) into y[seg[row]][col].
// ---------------------------------------------------------------------------
template <int BN, int MODE, int KTOT>
__global__ __launch_bounds__(512, 4) void gemm_stream(GArgs ga, int nrows) {
  constexpr int NI = BN / 16;
  constexpr int KT = KTOT / 32;
  constexpr int LDK = KTOT + 8;                 // pad 8 u16 = 16B
  constexpr int BEL = BN * KTOT;                // B elements
  constexpr int SIT = BEL / (512 * 8);          // staging iters
  constexpr int KSH = (KTOT == 256) ? 8 : 7;
  __shared__ u16 Bs[BN * LDK];
  __shared__ float redS[(MODE == 0) ? 128 : 1];
  __shared__ float redQ[(MODE == 0) ? 128 : 1];

  const int pb = blockIdx.y;
  const int t = threadIdx.x;
  const int w = t >> 6, lane = t & 63;
  const int laneM = lane & 15, kg = lane >> 4;
  const int r0 = blockIdx.x * 128 + w * 16;

  const u16* Bt = ga.Bt[pb];
  const float* bias = ga.bias[pb];

  int ra = r0 + laneM;
  if (ra >= nrows) ra = nrows - 1;

  short8 sreg[SIT];
  short8 af[KT];

  if constexpr (MODE == 0) {
    const float* A = (const float*)ga.A1[pb] + (size_t)ra * KTOT + kg * 8;
    float4 pf[8];
    // ---- issue B staging + A half-0: one parallel wall ----
#pragma unroll
    for (int si = 0; si < SIT; si++)
      sreg[si] = *(const short8*)(Bt + si * 4096 + t * 8);
#pragma unroll
    for (int kt = 0; kt < 4; kt++) {
      pf[2 * kt] = *(const float4*)(A + kt * 32);
      pf[2 * kt + 1] = *(const float4*)(A + kt * 32 + 4);
    }
    __builtin_amdgcn_sched_barrier(0);
#pragma unroll
    for (int kt = 0; kt < 4; kt++) {
      float4 v0 = pf[2 * kt], v1 = pf[2 * kt + 1];
      short8 s;
      s[0] = (short)f2bf(v0.x); s[1] = (short)f2bf(v0.y);
      s[2] = (short)f2bf(v0.z); s[3] = (short)f2bf(v0.w);
      s[4] = (short)f2bf(v1.x); s[5] = (short)f2bf(v1.y);
      s[6] = (short)f2bf(v1.z); s[7] = (short)f2bf(v1.w);
      af[kt] = s;
    }
    // B -> LDS (vmcnt already drained by the converts)
#pragma unroll
    for (int si = 0; si < SIT; si++) {
      int i = si * 4096 + t * 8;
      *(short8*)&Bs[(i >> KSH) * LDK + (i & (KTOT - 1))] = sreg[si];
    }
    // ---- A half-1 (pf reuse enforces ordering; wall mostly hidden) ----
#pragma unroll
    for (int kt = 0; kt < 4; kt++) {
      pf[2 * kt] = *(const float4*)(A + 128 + kt * 32);
      pf[2 * kt + 1] = *(const float4*)(A + 128 + kt * 32 + 4);
    }
    __builtin_amdgcn_sched_barrier(0);
#pragma unroll
    for (int kt = 0; kt < 4; kt++) {
      float4 v0 = pf[2 * kt], v1 = pf[2 * kt + 1];
      short8 s;
      s[0] = (short)f2bf(v0.x); s[1] = (short)f2bf(v0.y);
      s[2] = (short)f2bf(v0.z); s[3] = (short)f2bf(v0.w);
      s[4] = (short)f2bf(v1.x); s[5] = (short)f2bf(v1.y);
      s[6] = (short)f2bf(v1.z); s[7] = (short)f2bf(v1.w);
      af[4 + kt] = s;
    }
    if (t < 128) { redS[t] = 0.f; redQ[t] = 0.f; }
  } else {
    // ---- issue B staging + full-K A: one parallel wall ----
#pragma unroll
    for (int si = 0; si < SIT; si++)
      sreg[si] = *(const short8*)(Bt + si * 4096 + t * 8);
    const u16* A1 = (const u16*)ga.A1[pb] + (size_t)ra * HID + kg * 8;
    constexpr int K1 = (MODE == 1) ? KT / 2 : KT;
#pragma unroll
    for (int kt = 0; kt < K1; kt++) af[kt] = *(const short8*)(A1 + kt * 32);
    if constexpr (MODE == 1) {
      const u16* A2 = (const u16*)ga.A2[pb] + (size_t)ra * HID + kg * 8;
#pragma unroll
      for (int kt = 0; kt < KT / 2; kt++)
        af[KT / 2 + kt] = *(const short8*)(A2 + kt * 32);
    }
    __builtin_amdgcn_sched_barrier(0);
    // B -> LDS (counted vmcnt: waits B loads only; A stays in flight)
#pragma unroll
    for (int si = 0; si < SIT; si++) {
      int i = si * 4096 + t * 8;
      *(short8*)&Bs[(i >> KSH) * LDK + (i & (KTOT - 1))] = sreg[si];
    }
  }
  __syncthreads();

  // ---- steady state: pure LDS + MFMA ----
  f32x4 acc[NI];
#pragma unroll
  for (int ni = 0; ni < NI; ni++) acc[ni] = (f32x4){0.f, 0.f, 0.f, 0.f};

#pragma unroll
  for (int kt = 0; kt < KT; kt++) {
    const int k0 = kt * 32 + kg * 8;
    short8 a = af[kt];
#pragma unroll
    for (int ni = 0; ni < NI; ni++) {
      short8 b = *(const short8*)&Bs[(ni * 16 + laneM) * LDK + k0];
      acc[ni] = __builtin_amdgcn_mfma_f32_16x16x32_bf16(a, b, acc[ni], 0, 0, 0);
    }
  }

  // ---- epilogue ----
  float bcol[NI];
#pragma unroll
  for (int ni = 0; ni < NI; ni++) bcol[ni] = bias[ni * 16 + laneM];

  float ssum[NI], ssq[NI];
#pragma unroll
  for (int ni = 0; ni < NI; ni++) { ssum[ni] = 0.f; ssq[ni] = 0.f; }

#pragma unroll
  for (int r = 0; r < 4; r++) {
    int gr = r0 + kg * 4 + r;
    if (gr >= nrows) continue;
    float pw = 0.f;
    int sI = 0;
    if constexpr (MODE == 2) {
      sI = ga.seg[pb][gr];
      int cv = ga.cnt[pb][sI];
      pw = 1.f / (float)(cv > 1 ? cv : 1);
    }
#pragma unroll
    for (int ni = 0; ni < NI; ni++) {
      int col = ni * 16 + laneM;
      float v = acc[ni][r] + bcol[ni];
      if constexpr (MODE == 0) {
        v = leaky_f(v);
        ga.Cb[pb][(size_t)gr * BN + col] = f2bf(v);
        ssum[ni] += v;
        ssq[ni] += v * v;
      } else if constexpr (MODE == 1) {
        v = leaky_f(v);
        ga.Cb[pb][(size_t)gr * BN + col] = f2bf(v);
      } else {
        atomicAdd(&ga.y[pb][(size_t)sI * OUT_DIM + col], v * pw);
      }
    }
  }

  if constexpr (MODE == 0) {
#pragma unroll
    for (int ni = 0; ni < NI; ni++) {
      float a = ssum[ni], b = ssq[ni];
      a += __shfl_xor(a, 16); a += __shfl_xor(a, 32);
      b += __shfl_xor(b, 16); b += __shfl_xor(b, 32);
      if (kg == 0) {
        atomicAdd(&redS[ni * 16 + laneM], a);
        atomicAdd(&redQ[ni * 16 + laneM], b);
      }
    }
    __syncthreads();
    if (t < 128) {
      atomicAdd(&ga.bnsum[pb][t], redS[t]);
      atomicAdd(&ga.bnss[pb][t], redQ[t]);
    }
  }
}

// Weights -> bf16 transposed Bt[n][k]; SKIPS Bt0 (folded later with BN affine).
__global__ __launch_bounds__(256) void cvt_weightsA(CvtArgs a) {
  int i = blockIdx.x * 256 + threadIdx.x;
  if (i >= 2 * 106496) return;
  int p = i >= 106496;
  int j = i - p * 106496;
  const float* const* W = a.W + p * 6;
  u16* out = a.Bt + (size_t)p * 106496;
  if (j < 32768) {
    int n = j >> 8, k = j & 255;
    out[j] = f2bf(W[0][k * 128 + n]);
  } else if (j < 65536) {
    return;
  } else if (j < 98304) {
    int q = j - 65536, n = q >> 8, k = q & 255;
    out[j] = f2bf(k < 128 ? W[3][k * 128 + n] : W[4][(k - 128) * 128 + n]);
  } else {
    int q = j - 98304, n = q >> 7, k = q & 127;
    out[j] = f2bf(W[5][k * 64 + n]);
  }
}

// abc layout: a[256] | c[256] | nc[256] | bias0p[256]
__global__ void bn_final(const float* __restrict__ bnstat,
                         const float* __restrict__ g0, const float* __restrict__ b0,
                         const float* __restrict__ g1, const float* __restrict__ b1,
                         float* __restrict__ abc) {
  int t = threadIdx.x;  // 256
  int p = t >> 7, cix = t & 127;
  const float* bs = bnstat + p * 256;
  float mu = bs[cix] * (1.f / N_NODES);
  float var = bs[128 + cix] * (1.f / N_NODES) - mu * mu;
  float rs = rsqrtf(var + EPS);
  const float* g = p ? g1 : g0;
  const float* b = p ? b1 : b0;
  float av = g[cix] * rs;
  float cv = b[cix] - mu * av;
  abc[t] = av;
  abc[256 + t] = cv;
  abc[512 + t] = (av != 0.f) ? (-cv / av) : 0.f;
}

// Fold BN affine into layer-0 weights.
__global__ __launch_bounds__(256) void cvt_fold(
    const float* __restrict__ Wl0_0, const float* __restrict__ Wr0_0,
    const float* __restrict__ Wl0_1, const float* __restrict__ Wr0_1,
    const float* __restrict__ b0_0, const float* __restrict__ b0_1,
    float* __restrict__ abc, u16* __restrict__ BtAll) {
  int i = blockIdx.x * 256 + threadIdx.x;
  if (i < 65536) {
    int p = i >> 15, q = i & 32767;
    int n = q >> 8, k = q & 255;
    const float* Wl = p ? Wl0_1 : Wl0_0;
    const float* Wr = p ? Wr0_1 : Wr0_0;
    float wv = (k < 128) ? Wl[k * 128 + n] : Wr[(k - 128) * 128 + n];
    float av = abc[p * 128 + (k & 127)];
    BtAll[(size_t)p * 106496 + 32768 + q] = f2bf(wv * av);
  } else if (i < 65536 + 256) {
    int j = i - 65536;
    int p = j >> 7, n = j & 127;
    const float* Wl = p ? Wl0_1 : Wl0_0;
    const float* Wr = p ? Wr0_1 : Wr0_0;
    const float* c = abc + 256 + p * 128;
    float s = (p ? b0_1 : b0_0)[n];
    for (int k = 0; k < 128; k++) s += c[k] * (Wl[k * 128 + n] + Wr[k * 128 + n]);
    abc[768 + j] = s;
  }
}

// pooling counts
__global__ void cnt_count(EdgeArgs ea, int* __restrict__ cnt) {
  int i = blockIdx.x * blockDim.x + threadIdx.x;
  if (i < 2 * N_NODES) {
    int p = i >= N_NODES;
    int k = i - p * N_NODES;
    atomicAdd(&cnt[p * M_ROWS + ea.seg[p][k]], 1);
  }
}

// --------- Phase A: partition edges into NSB super-buckets ------------------
// packed: dst_local(9b) << 17 | src(16b). Tile = 2048 edges, block-local
// counting sort, wave-per-bucket chunk copy-out.
__global__ __launch_bounds__(256) void part_edges(EdgeArgs ea, u32* __restrict__ sbuf,
                                                  int* __restrict__ gcursor) {
  __shared__ u32 lpack[2048];
  __shared__ int hist[NSB], base[NSB], gbase[NSB], lofs[NSB];
  int t = threadIdx.x;
  int e0 = blockIdx.x * 2048;
  for (int i = t; i < NSB; i += 256) hist[i] = 0;
  __syncthreads();
  u32 myp[8];
  int myb[8];
#pragma unroll
  for (int q = 0; q < 8; q++) {
    int i = e0 + q * 256 + t;
    int b = -1;
    u32 pk = 0;
    if (i < 2 * E_EDGES) {
      int p = i >= E_EDGES;
      int j = i - p * E_EDGES;
      int d = p * N_NODES + ea.dst[p][j];
      int s = ea.src[p][j];
      b = d >> SB_BITS;
      pk = ((u32)(d & (SB_SIZE - 1)) << 17) | (u32)s;
      atomicAdd(&hist[b], 1);
    }
    myb[q] = b;
    myp[q] = pk;
  }
  __syncthreads();
  if (t == 0) {
    int acc = 0;
    for (int b = 0; b < NSB; b++) { base[b] = acc; acc += hist[b]; }
  }
  __syncthreads();
  for (int i = t; i < NSB; i += 256) {
    lofs[i] = 0;
    gbase[i] = atomicAdd(&gcursor[i], hist[i]);
  }
  __syncthreads();
#pragma unroll
  for (int q = 0; q < 8; q++) {
    if (myb[q] >= 0) {
      int pos = atomicAdd(&lofs[myb[q]], 1);
      lpack[base[myb[q]] + pos] = myp[q];
    }
  }
  __syncthreads();
  int wid = t >> 6, lane = t & 63;
  for (int b = wid; b < NSB; b += 4) {
    int n = hist[b], lb = base[b], gb = gbase[b];
    for (int k = lane; k < n; k += 64)
      sbuf[(size_t)b * SB_CAP + gb + k] = lpack[lb + k];
  }
}

// --------- Phase B: per-super-bucket CSR build (one block per bucket) -------
// 196 blocks x 512 threads; 512-node buckets -> ~8K edges/block.
__global__ __launch_bounds__(512) void build_csr(
    const u32* __restrict__ sbuf, const int* __restrict__ gtot,
    int* __restrict__ offs, float* __restrict__ dinv, u16* __restrict__ colu) {
  __shared__ int ldeg[SB_SIZE];
  __shared__ int lcur[SB_SIZE];
  __shared__ int wsum[8];
  __shared__ int sbase_s;
  int b = blockIdx.x, t = threadIdx.x;
  int lane = t & 63, wid = t >> 6;
  ldeg[t] = 0;
  if (t < 64) {
    // edge_base = sum of gtot[0..b) via 64-lane masked sum + butterfly
    int s = 0;
    for (int i = lane; i < b; i += 64) s += gtot[i];
#pragma unroll
    for (int off = 1; off < 64; off <<= 1) s += __shfl_xor(s, off, 64);
    if (lane == 0) sbase_s = s;
  }
  __syncthreads();
  const int cnt = gtot[b];
  const int edge_base = sbase_s;
  const int node0 = b << SB_BITS;
  int nend = 2 * N_NODES - node0;
  if (nend > SB_SIZE) nend = SB_SIZE;
  const u32* me = sbuf + (size_t)b * SB_CAP;
  for (int k = t; k < cnt; k += 512) atomicAdd(&ldeg[me[k] >> 17], 1);
  __syncthreads();
  // block scan over 512 (one node per thread)
  int d = ldeg[t];
  int incl = d;
#pragma unroll
  for (int off = 1; off < 64; off <<= 1) {
    int u = __shfl_up(incl, off, 64);
    if (lane >= off) incl += u;
  }
  if (lane == 63) wsum[wid] = incl;
  __syncthreads();
  if (t == 0) {
    int acc = 0;
#pragma unroll
    for (int i = 0; i < 8; i++) { int v = wsum[i]; wsum[i] = acc; acc += v; }
  }
  __syncthreads();
  int ex = wsum[wid] + incl - d;
  if (t < nend) {
    offs[node0 + t] = edge_base + ex;
    dinv[node0 + t] = d > 0 ? 1.f / (float)d : -1.f;
  }
  lcur[t] = ex;
  __syncthreads();
  for (int k = t; k < cnt; k += 512) {
    u32 v = me[k];
    int pos = atomicAdd(&lcur[v >> 17], 1);
    colu[edge_base + pos] = (u16)(v & 0xFFFFu);
  }
  if (b == 0 && t == 0) offs[2 * N_NODES] = 2 * E_EDGES;
}

// --------- mean-aggregate v2: 1 wave/node, 4 edge-groups x 16 col-lanes ----
// Lane loads uint4 (16B = 8 bf16 cols); main loop = 16 edges/iter -> 4
// independent gathers per lane in flight. dinv<0 marks deg==0 -> nc[col].
__global__ __launch_bounds__(256) void aggregate_bf16(
    const u16* __restrict__ h, const u16* __restrict__ colu,
    const int* __restrict__ offs, const float* __restrict__ dinv,
    const float* __restrict__ nc, u16* __restrict__ agg) {
  int gw = (blockIdx.x * 256 + threadIdx.x) >> 6;
  int lane = threadIdx.x & 63;
  if (gw >= 2 * N_NODES) return;
  int panel = gw >= N_NODES;
  const uint4* hp = (const uint4*)(h + (size_t)panel * N_NODES * 128);
  int grp = lane >> 4, li = lane & 15;
  int s = offs[gw], e = offs[gw + 1];
  float a[8];
#pragma unroll
  for (int k = 0; k < 8; k++) a[k] = 0.f;

  auto acc8 = [&](uint4 v) {
    a[0] += bf2f_lo(v.x); a[1] += bf2f_hi(v.x);
    a[2] += bf2f_lo(v.y); a[3] += bf2f_hi(v.y);
    a[4] += bf2f_lo(v.z); a[5] += bf2f_hi(v.z);
    a[6] += bf2f_lo(v.w); a[7] += bf2f_hi(v.w);
  };

  int j = s;
  for (; j + 16 <= e; j += 16) {
    int c0 = colu[j + grp];
    int c1 = colu[j + 4 + grp];
    int c2 = colu[j + 8 + grp];
    int c3 = colu[j + 12 + grp];
    uint4 v0 = hp[(size_t)c0 * 16 + li];
    uint4 v1 = hp[(size_t)c1 * 16 + li];
    uint4 v2 = hp[(size_t)c2 * 16 + li];
    uint4 v3 = hp[(size_t)c3 * 16 + li];
    acc8(v0); acc8(v1); acc8(v2); acc8(v3);
  }
  for (; j + 4 <= e; j += 4) {
    int c = colu[j + grp];
    uint4 v = hp[(size_t)c * 16 + li];
    acc8(v);
  }
  if (j + grp < e) {
    int c = colu[j + grp];
    uint4 v = hp[(size_t)c * 16 + li];
    acc8(v);
  }

#pragma unroll
  for (int k = 0; k < 8; k++) {
    a[k] += __shfl_xor(a[k], 16);
    a[k] += __shfl_xor(a[k], 32);
  }

  if (grp == 0) {
    float di = dinv[gw];
    float o[8];
    if (di < 0.f) {
      const float* np = nc + panel * 128 + li * 8;
#pragma unroll
      for (int k = 0; k < 8; k++) o[k] = np[k];
    } else {
#pragma unroll
      for (int k = 0; k < 8; k++) o[k] = a[k] * di;
    }
    uint4 ov;
    ov.x = ((u32)f2bf(o[1]) << 16) | (u32)f2bf(o[0]);
    ov.y = ((u32)f2bf(o[3]) << 16) | (u32)f2bf(o[2]);
    ov.z = ((u32)f2bf(o[5]) << 16) | (u32)f2bf(o[4]);
    ov.w = ((u32)f2bf(o[7]) << 16) | (u32)f2bf(o[6]);
    ((uint4*)agg)[(size_t)gw * 16 + li] = ov;
  }
}

__global__ __launch_bounds__(256) void mse_kernel(const float* __restrict__ yb,
                                                  const float* __restrict__ x0,
                                                  const float* __restrict__ x1,
                                                  float* __restrict__ acc) {
  __shared__ float ls[256];
  int pb = blockIdx.y;
  const float* y = yb + (size_t)pb * M_ROWS * OUT_DIM;
  const float* x = pb ? x1 : x0;
  float s = 0.f;
  for (int i = blockIdx.x * 256 + threadIdx.x; i < M_ROWS * OUT_DIM; i += gridDim.x * 256) {
    float d = y[i] - x[i];
    s += d * d;
  }
  ls[threadIdx.x] = s;
  __syncthreads();
  for (int o = 128; o > 0; o >>= 1) {
    if (threadIdx.x < o) ls[threadIdx.x] += ls[threadIdx.x + o];
    __syncthreads();
  }
  if (threadIdx.x == 0) atomicAdd(&acc[pb], ls[0]);
}

__global__ void finalize(const float* __restrict__ acc, float* __restrict__ out) {
  int t = threadIdx.x;
  if (t < 2) out[t] = acc[t] * (1.f / (float)(M_ROWS * OUT_DIM));
}

// ---------------------------------------------------------------------------
extern "C" void kernel_launch(void* const* d_in, const int* in_sizes, int n_in,
                              void* d_out, int out_size, void* d_ws, size_t ws_size,
                              hipStream_t stream) {
  (void)in_sizes; (void)n_in; (void)out_size; (void)ws_size;
  const float* feat[2] = {(const float*)d_in[0], (const float*)d_in[1]};
  const float* xmat[2] = {(const float*)d_in[2], (const float*)d_in[3]};
  const int* esrc[2] = {(const int*)d_in[4], (const int*)d_in[6]};
  const int* edst[2] = {(const int*)d_in[5], (const int*)d_in[7]};
  const int* aseg[2] = {(const int*)d_in[8], (const int*)d_in[9]};

  struct P {
    const float *W_mlp, *b_mlp, *bn_g, *bn_b, *Wl0, *Wr0, *b0, *Wl1, *Wr1, *b1, *Wp, *bp;
  } prm[2];
  for (int p = 0; p < 2; p++) {
    int b = 10 + 12 * p;
    prm[p] = {(const float*)d_in[b + 0], (const float*)d_in[b + 1],
              (const float*)d_in[b + 2], (const float*)d_in[b + 3],
              (const float*)d_in[b + 4], (const float*)d_in[b + 5],
              (const float*)d_in[b + 6], (const float*)d_in[b + 7],
              (const float*)d_in[b + 8], (const float*)d_in[b + 9],
              (const float*)d_in[b + 10], (const float*)d_in[b + 11]};
  }

  char* w = (char*)d_ws;
  auto carve = [&](size_t bytes) -> char* {
    char* r = w;
    w += (bytes + 255) & ~(size_t)255;
    return r;
  };
  // ---- zeroed region (single memset) ----
  char* zbase = w;
  int* gcursor = (int*)carve(NSB * 4);
  int* cnt    = (int*)carve((size_t)2 * M_ROWS * 4);
  float* bnstat = (float*)carve(2 * 256 * 4);
  float* lossacc = (float*)carve(64 * 4);
  float* zerobuf = (float*)carve(256 * 4);
  float* yb   = (float*)carve((size_t)2 * M_ROWS * OUT_DIM * 4);
  size_t zbytes = (size_t)(w - zbase);
  // ---- non-zeroed ----
  u16* hb   = (u16*)carve((size_t)2 * N_NODES * HID * 2);
  u16* aggb = (u16*)carve((size_t)2 * N_NODES * HID * 2);
  u32* sbuf = (u32*)aggb;  // aliased: sbuf (9.6MB) dead before first aggregate write
  float* dinv = (float*)carve((size_t)2 * N_NODES * 4);
  float* abc = (float*)carve(1024 * 4);  // a|c|nc|bias0p
  int* offs = (int*)carve((size_t)(2 * N_NODES + 1) * 4);
  u16* colu = (u16*)carve((size_t)2 * E_EDGES * 2);
  u16* BtAll = (u16*)carve((size_t)2 * 106496 * 2);

  const int TWO_N = 2 * N_NODES;

  EdgeArgs ea;
  for (int p = 0; p < 2; p++) { ea.src[p] = esrc[p]; ea.dst[p] = edst[p]; ea.seg[p] = aseg[p]; }

  CvtArgs ca;
  for (int p = 0; p < 2; p++) {
    ca.W[p * 6 + 0] = prm[p].W_mlp; ca.W[p * 6 + 1] = prm[p].Wl0;
    ca.W[p * 6 + 2] = prm[p].Wr0;   ca.W[p * 6 + 3] = prm[p].Wl1;
    ca.W[p * 6 + 4] = prm[p].Wr1;   ca.W[p * 6 + 5] = prm[p].Wp;
  }
  ca.Bt = BtAll;

  auto mkga = [&](int mode, int layer) {
    GArgs g{};
    for (int p = 0; p < 2; p++) {
      u16* hp = hb + (size_t)p * N_NODES * HID;
      const u16* btp = BtAll + (size_t)p * 106496;
      g.Cb[p] = hp;
      g.bnsum[p] = bnstat + p * 256;
      g.bnss[p] = bnstat + p * 256 + 128;
      g.seg[p] = aseg[p];
      g.cnt[p] = cnt + p * M_ROWS;
      g.y[p] = yb + (size_t)p * M_ROWS * OUT_DIM;
      if (mode == 0) {
        g.A1[p] = feat[p];
        g.Bt[p] = btp;
        g.bias[p] = prm[p].b_mlp;
      } else if (mode == 1) {
        g.A1[p] = hp;
        g.A2[p] = aggb + (size_t)p * N_NODES * HID;
        g.Bt[p] = btp + (layer ? 65536 : 32768);
        g.bias[p] = layer ? prm[p].b1 : (const float*)(abc + 768 + p * 128);
      } else {
        g.A1[p] = hp;
        g.Bt[p] = btp + 98304;
        g.bias[p] = prm[p].bp;
      }
    }
    return g;
  };

  const int GX = (N_NODES + 127) / 128;  // 391 blocks of 128 rows (8 waves x 16)

  hipMemsetAsync(zbase, 0, zbytes, stream);
  cvt_weightsA<<<(2 * 106496 + 255) / 256, 256, 0, stream>>>(ca);
  // edge partition + CSR build
  part_edges<<<(2 * E_EDGES + 2047) / 2048, 256, 0, stream>>>(ea, sbuf, gcursor);
  build_csr<<<NSB, 512, 0, stream>>>(sbuf, gcursor, offs, dinv, colu);
  cnt_count<<<(TWO_N + 255) / 256, 256, 0, stream>>>(ea, cnt);
  // encode (both panels) + BN stats; h stays PRE-BN (affine folded downstream)
  gemm_stream<128, 0, IN_DIM><<<dim3(GX, 2), 512, 0, stream>>>(mkga(0, 0), N_NODES);
  bn_final<<<1, 256, 0, stream>>>(bnstat, prm[0].bn_g, prm[0].bn_b,
                                  prm[1].bn_g, prm[1].bn_b, abc);
  cvt_fold<<<(65536 + 256 + 255) / 256, 256, 0, stream>>>(
      prm[0].Wl0, prm[0].Wr0, prm[1].Wl0, prm[1].Wr0, prm[0].b0, prm[1].b0,
      abc, BtAll);
  // SAGE layer 0 (raw h + BN-folded weights; deg==0 rows patched with nc)
  aggregate_bf16<<<(TWO_N * 64 + 255) / 256, 256, 0, stream>>>(
      hb, colu, offs, dinv, abc + 512, aggb);
  gemm_stream<128, 1, 2 * HID><<<dim3(GX, 2), 512, 0, stream>>>(mkga(1, 0), N_NODES);
  // SAGE layer 1 (in-place h; deg==0 rows -> 0)
  aggregate_bf16<<<(TWO_N * 64 + 255) / 256, 256, 0, stream>>>(
      hb, colu, offs, dinv, zerobuf, aggb);
  gemm_stream<128, 1, 2 * HID><<<dim3(GX, 2), 512, 0, stream>>>(mkga(1, 1), N_NODES);
  // projection + mean-pool
  gemm_stream<64, 2, HID><<<dim3(GX, 2), 512, 0, stream>>>(mkga(2, 0), N_NODES);
  mse_kernel<<<dim3(128, 2), 256, 0, stream>>>(yb, xmat[0], xmat[1], lossacc);
  finalize<<<1, 64, 0, stream>>>(lossacc, (float*)d_out);
}